// Round 4
// baseline (542.973 us; speedup 1.0000x reference)
//
#include <hip/hip_runtime.h>
#include <hip/hip_bf16.h>

// Problem constants
#define B_    8
#define C_    96
#define N_    3136      // 56*56
#define COUT_ 192
#define NTOK_ 25088     // B_*N_
#define BN_EPS 1e-5f

#define CROW 200        // conv cat LDS token-row stride in bf16 (192+8): 400B = 25*16 odd -> conflict-free
#define BNC  (B_ * N_ * C_)
#define NSPLIT 4
#define NT98  98        // 32-row K tiles per batch (3136/32)

// K2 LDS geometry (bytes), per buffer:
//  Kh: 32 rows * 208B (13 chunks of 16B: 12 data + 1 pad; 13 odd -> bank-perm) = 6656, pad to 7*1024
//  Kl: same, at +7168
//  V : 96 ch * 80B (5 chunks: 4 data + 1 pad) = 7680, pad to 8*1024, at +14336
#define K2_KL_OFF 7168
#define K2_V_OFF  14336
#define K2_BUFSZ  22528

typedef __hip_bfloat16 bf16;
typedef unsigned short u16;
typedef unsigned int u32;
typedef __attribute__((ext_vector_type(8))) short short8;    // 8 bf16 = 16B (MFMA A/B frag)
typedef __attribute__((ext_vector_type(16))) float f32x16;   // 32x32 MFMA C/D frag

__device__ __forceinline__ u16 f2bf(float f) {
    union { __hip_bfloat16 h; u16 u; } cv;
    cv.h = __float2bfloat16(f);
    return cv.u;
}
__device__ __forceinline__ float bf2f(u16 v) {
    union { u16 u; __hip_bfloat16 h; } cv;
    cv.u = v;
    return __bfloat162float(cv.h);
}
__device__ __forceinline__ u32 packbf2(float lo, float hi) {
    return ((u32)f2bf(hi) << 16) | (u32)f2bf(lo);
}

// async global->LDS DMA, 16B per lane: LDS dest = WAVE-UNIFORM base + lane*16.
__device__ __forceinline__ void gload_lds16(const void* g, void* l) {
    __builtin_amdgcn_global_load_lds((const __attribute__((address_space(1))) void*)g,
                                     (__attribute__((address_space(3))) void*)l,
                                     16, 0, 0);
}

// ---------------------------------------------------------------------------
// K1: x [B][C][N] fp32 -> xt_hi/xt_lo [B][N][C] bf16 (token-major, hi/lo split)
//                         xc_hi [B][C][N] bf16 (channel-major, V staged from here)
// Fused: per-token squared-norm partial sums (32 channels per block) -> norm2.
__global__ __launch_bounds__(256) void transpose_split(const float* __restrict__ x,
                                                       u16* __restrict__ xt_hi,
                                                       u16* __restrict__ xt_lo,
                                                       u16* __restrict__ xc_hi,
                                                       float* __restrict__ norm2) {
    __shared__ float tile[32][33];
    __shared__ float nrm[32];
    const int nb = blockIdx.x * 32;
    const int cb = blockIdx.y * 32;
    const int b  = blockIdx.z;
    const int tid = threadIdx.x;
    const int tx = tid & 31;
    const int ty = tid >> 5;
    if (tid < 32) nrm[tid] = 0.0f;
    float psum = 0.0f;
#pragma unroll
    for (int r = 0; r < 32; r += 8) {
        size_t idx = ((size_t)b * C_ + cb + ty + r) * N_ + nb + tx;
        float v = x[idx];
        tile[ty + r][tx] = v;
        xc_hi[idx] = f2bf(v);
        psum = fmaf(v, v, psum);
    }
    __syncthreads();               // tile visible; nrm init done
    atomicAdd(&nrm[tx], psum);     // LDS atomic, 8 adders per slot
#pragma unroll
    for (int r = 0; r < 32; r += 8) {
        float v = tile[tx][ty + r];
        u16 h = f2bf(v);
        size_t o = ((size_t)b * N_ + nb + ty + r) * C_ + cb + tx;
        xt_hi[o] = h;
        xt_lo[o] = f2bf(v - bf2f(h));
    }
    __syncthreads();               // nrm complete
    if (tid < 32)
        atomicAdd(&norm2[(size_t)b * N_ + nb + tid], nrm[tid]);
}

// K1b: conv_w [O][2C] fp32 -> whi/wlo bf16 (same [o][c] layout, hi/lo split)
__global__ __launch_bounds__(256) void cast_w(const float* __restrict__ w,
                                              u16* __restrict__ whi,
                                              u16* __restrict__ wlo) {
    int i = blockIdx.x * 256 + threadIdx.x;
    if (i >= COUT_ * 2 * C_) return;
    float v = w[i];
    u16 h = f2bf(v);
    whi[i] = h;
    wlo[i] = f2bf(v - bf2f(h));
}

// K1c: global max of norm2 (single block)
__global__ __launch_bounds__(256) void norm_max(const float* __restrict__ norm2,
                                                int* __restrict__ maxbits) {
    const int tid = threadIdx.x;
    float m = 0.0f;
    for (int i = tid; i < NTOK_; i += 256) m = fmaxf(m, norm2[i]);
#pragma unroll
    for (int d = 1; d < 64; d <<= 1) m = fmaxf(m, __shfl_xor(m, d));
    __shared__ float wmax[4];
    if ((tid & 63) == 0) wmax[tid >> 6] = m;
    __syncthreads();
    if (tid == 0) {
        float mm = fmaxf(fmaxf(wmax[0], wmax[1]), fmaxf(wmax[2], wmax[3]));
        *maxbits = __float_as_int(mm);
    }
}

// ---------------------------------------------------------------------------
// K2: MFMA flash attention, transposed-S, 4-way split-K.
// R15: R14's packed 192B/64B rows were a 16-way bank conflict (granule
// stride even): SQ_LDS_BANK_CONFLICT 3.8M->16.9M. Fix: odd-multiple-of-16B
// row strides -- K rows 208B (13 granules, perm mod 8), V rows 80B (5).
// DMA source stays near-contiguous (r*192+c*16, 1/13 pad waste), dest linear,
// read offsets match placement (rule #21 satisfied with no XOR).
// Pipeline (1 barrier/tile, double-buffered, prefetch-at-top) unchanged.
__global__ __launch_bounds__(256, 3) void flash_attn_mfma32(const u16* __restrict__ xt_hi,
                                                            const u16* __restrict__ xt_lo,
                                                            const u16* __restrict__ xc_hi,
                                                            const float* __restrict__ norm2,
                                                            const int* __restrict__ maxbits,
                                                            float* __restrict__ attT,
                                                            float* __restrict__ l_arr) {
    __shared__ __align__(16) char LDSU[2][K2_BUFSZ];
    const int b     = blockIdx.y;
    const int i0    = blockIdx.x * 128;
    const int split = blockIdx.z;
    const int kt0   = (NT98 * split) / NSPLIT;
    const int kt1   = (NT98 * (split + 1)) / NSPLIT;
    const int tid   = threadIdx.x;
    const int lane  = tid & 63;
    const int w     = tid >> 6;
    const int col   = lane & 31;
    const int g     = lane >> 5;

    const u16* th = xt_hi + (size_t)b * N_ * C_;
    const u16* tl = xt_lo + (size_t)b * N_ * C_;
    const u16* vh = xc_hi + (size_t)b * C_ * N_;

    // Staging: 22 DMA slots of 1KB per buffer (Kh 0..6, Kl 7..13, V 14..21).
    // Wave w owns slots w+4j. Per-slot: wave-uniform LDS dest (HW adds
    // lane*16) + per-lane global source offset (tile term added at issue).
    u32 loff[6], dofs[6];
#pragma unroll
    for (int j = 0; j < 6; j++) {
        int s = w + 4 * j;
        if (s >= 22) { loff[j] = 0; dofs[j] = 0; continue; }
        if (s < 14) {                 // K hi/lo
            int kind = s < 7 ? 0 : 1;
            int t = s - kind * 7;
            int p = t * 64 + lane;    // physical 16B chunk 0..447
            int r = p / 13, c = p % 13;
            if (c > 11) c = 11;       // row pad chunk: duplicate read
            loff[j] = (r < 32) ? (u32)(r * 192 + c * 16) : 0u;   // tail pad
            dofs[j] = (u32)(kind * K2_KL_OFF + t * 1024);
        } else {                      // V
            int t = s - 14;
            int p = t * 64 + lane;    // 0..511
            int ch = p / 5, c = p % 5;
            if (c > 3) c = 3;
            loff[j] = (ch < 96) ? (u32)(ch * (N_ * 2) + c * 16) : 0u;
            dofs[j] = (u32)(K2_V_OFF + t * 1024);
        }
    }

    // Q B-frags from global, once (lane holds its own q-row)
    const int qrow  = i0 + w * 32 + col;
    const int qrowc = qrow < N_ ? qrow : N_ - 1;
    short8 qh[6], ql[6];
#pragma unroll
    for (int kc = 0; kc < 6; kc++) {
        qh[kc] = *(const short8*)&th[(size_t)qrowc * C_ + kc * 16 + g * 8];
        ql[kc] = *(const short8*)&tl[(size_t)qrowc * C_ + kc * 16 + g * 8];
    }
    const float maxn2 = __int_as_float(*maxbits);
    const float m_i   = sqrtf(norm2[(size_t)b * N_ + qrowc] * maxn2);
    float l_acc = 0.0f;
    f32x16 O0 = {0}, O1 = {0}, O2 = {0};

    // stage tile kt into buffer nbuf (async DMA; drained at next barrier)
    auto stage = [&](int nbuf, int kt) {
        const u32 ktK = (u32)kt * 6144u;   // 32 rows * 192B
        const u32 ktV = (u32)kt * 64u;     // 32 tokens * 2B
#pragma unroll
        for (int j = 0; j < 6; j++) {
            int s = w + 4 * j;
            if (s >= 22) break;
            const char* sb = (s < 7)  ? (const char*)th + ktK
                           : (s < 14) ? (const char*)tl + ktK
                                      : (const char*)vh + ktV;
            gload_lds16(sb + loff[j], (char*)&LDSU[nbuf][0] + dofs[j]);
        }
    };

    stage(0, kt0);
    __syncthreads();

    const int g16 = g * 16;
    int buf = 0;
    for (int kt = kt0; kt < kt1; kt++) {
        // (1) prefetch next tile into back buffer (in flight across compute)
        if (kt + 1 < kt1) stage(buf ^ 1, kt + 1);

        const char* Lb = (const char*)&LDSU[buf][0];

        // (2) QK^T: S[k=0..31][q=col], hi/lo split (3 MFMA per k-chunk)
        f32x16 S = {0};
        __builtin_amdgcn_s_setprio(1);
#pragma unroll
        for (int kc = 0; kc < 6; kc++) {
            const int o2 = col * 208 + kc * 32 + g16;
            short8 kh = *(const short8*)(Lb + o2);
            short8 kl = *(const short8*)(Lb + K2_KL_OFF + o2);
            S = __builtin_amdgcn_mfma_f32_32x32x16_bf16(kh, ql[kc], S, 0, 0, 0);
            S = __builtin_amdgcn_mfma_f32_32x32x16_bf16(kl, qh[kc], S, 0, 0, 0);
            S = __builtin_amdgcn_mfma_f32_32x32x16_bf16(kh, qh[kc], S, 0, 0, 0);
        }
        __builtin_amdgcn_s_setprio(0);

        // (3) softmax numerators + bf16 pack
        float p[16];
#pragma unroll
        for (int r = 0; r < 16; r++) {
            p[r] = __expf(S[r] - m_i);
            l_acc += p[r];
        }
        u32 w8[8];
#pragma unroll
        for (int q = 0; q < 8; q++) w8[q] = packbf2(p[2 * q], p[2 * q + 1]);

        // (4) PV from V-LDS (rows 80B: conflict-free)
        __builtin_amdgcn_s_setprio(1);
#pragma unroll
        for (int kc = 0; kc < 2; kc++) {
            const int qb = kc * 4;
            u32 a0 = w8[qb + 0], a1 = w8[qb + 1];
            u32 a2 = w8[qb + 2], a3 = w8[qb + 3];
            u32 s0 = __shfl_xor((int)a0, 32), s1 = __shfl_xor((int)a1, 32);
            u32 s2 = __shfl_xor((int)a2, 32), s3 = __shfl_xor((int)a3, 32);
            union { short8 v; u32 u[4]; } Bf;
            Bf.u[0] = g ? s2 : a0;
            Bf.u[1] = g ? s3 : a1;
            Bf.u[2] = g ? a2 : s0;
            Bf.u[3] = g ? a3 : s1;
            const int vo = K2_V_OFF + col * 80 + kc * 32 + g16;
            short8 v0 = *(const short8*)(Lb + vo);
            short8 v1 = *(const short8*)(Lb + vo + 2560);   // +32 ch * 80B
            short8 v2 = *(const short8*)(Lb + vo + 5120);   // +64 ch * 80B
            O0 = __builtin_amdgcn_mfma_f32_32x32x16_bf16(v0, Bf.v, O0, 0, 0, 0);
            O1 = __builtin_amdgcn_mfma_f32_32x32x16_bf16(v1, Bf.v, O1, 0, 0, 0);
            O2 = __builtin_amdgcn_mfma_f32_32x32x16_bf16(v2, Bf.v, O2, 0, 0, 0);
        }
        __builtin_amdgcn_s_setprio(0);

        __syncthreads();     // drains my DMAs + all waves' LDS reads done
        buf ^= 1;
    }

    if (qrow < N_) {
        float* ab = attT + (size_t)b * C_ * N_ + qrow;
#pragma unroll
        for (int r = 0; r < 16; r++) {
            int c = (r & 3) + 8 * (r >> 2) + 4 * g;
            atomicAdd(&ab[(size_t)(c)      * N_], O0[r]);
            atomicAdd(&ab[(size_t)(c + 32) * N_], O1[r]);
            atomicAdd(&ab[(size_t)(c + 64) * N_], O2[r]);
        }
        float l_tot = l_acc + __shfl_xor(l_acc, 32);
        if (g == 0) atomicAdd(&l_arr[(size_t)b * N_ + qrow], l_tot);
    }
}

// ---------------------------------------------------------------------------
// K3: MFMA 1x1 conv. R15: 32-token tiles / 128-thread blocks (784 blocks,
// 25.6KB LDS -> ~6 blocks/CU = 12 waves vs R14's 1.5 blocks) to hide the
// 72 scattered 16B weight loads per wave. BN sum/sumsq fused into epilogue
// (half-wave shuffle reduce + 2 atomics per channel-frag) -> K4 deleted.
__global__ __launch_bounds__(128, 3) void conv_mfma(const float* __restrict__ x,
                                                    const float* __restrict__ attT,
                                                    const float* __restrict__ l_arr,
                                                    const u16* __restrict__ whi,
                                                    const u16* __restrict__ wlo,
                                                    const float* __restrict__ convb,
                                                    float* __restrict__ y,
                                                    float* __restrict__ bns) {
    __shared__ u16 ch[32 * CROW];
    __shared__ u16 cl[32 * CROW];
    __shared__ float invl[32];
    const int b   = blockIdx.x / (N_ / 32);
    const int n0  = (blockIdx.x % (N_ / 32)) * 32;
    const int tid = threadIdx.x;

    if (tid < 32) invl[tid] = 1.0f / l_arr[(size_t)b * N_ + n0 + tid];
    __syncthreads();

    const float* xb = x    + (size_t)b * C_ * N_ + n0;
    const float* ab = attT + (size_t)b * C_ * N_ + n0;
    for (int e = tid; e < 32 * C_; e += 128) {
        int c = e >> 5, t = e & 31;
        float xv = xb[(size_t)c * N_ + t];
        float au = ab[(size_t)c * N_ + t];
        float xj = fmaxf(xv - au * invl[t], 0.0f);
        u16 h1 = f2bf(xv);
        ch[t * CROW + c] = h1;
        cl[t * CROW + c] = f2bf(xv - bf2f(h1));
        u16 h2 = f2bf(xj);
        ch[t * CROW + C_ + c] = h2;
        cl[t * CROW + C_ + c] = f2bf(xj - bf2f(h2));
    }
    __syncthreads();

    const int lane = tid & 63;
    const int w    = tid >> 6;        // 0..1
    const int col  = lane & 31;       // token within tile
    const int g    = lane >> 5;
    const int m0   = w * 3;           // wave's 3 m-tiles (96 channels)

    f32x16 A[3] = {{0}, {0}, {0}};
#pragma unroll
    for (int ks = 0; ks < 12; ks++) {
        const int k0 = ks * 16;
        short8 bh = *(const short8*)&ch[col * CROW + k0 + g * 8];
        short8 bl = *(const short8*)&cl[col * CROW + k0 + g * 8];
#pragma unroll
        for (int mt = 0; mt < 3; mt++) {
            const size_t wo = (size_t)((m0 + mt) * 32 + col) * (2 * C_) + k0 + g * 8;
            short8 ah = *(const short8*)&whi[wo];
            short8 al = *(const short8*)&wlo[wo];
            A[mt] = __builtin_amdgcn_mfma_f32_32x32x16_bf16(ah, bl, A[mt], 0, 0, 0);
            A[mt] = __builtin_amdgcn_mfma_f32_32x32x16_bf16(al, bh, A[mt], 0, 0, 0);
            A[mt] = __builtin_amdgcn_mfma_f32_32x32x16_bf16(ah, bh, A[mt], 0, 0, 0);
        }
    }

    float* yb = y + (size_t)b * COUT_ * N_ + n0 + col;
#pragma unroll
    for (int mt = 0; mt < 3; mt++)
#pragma unroll
        for (int r = 0; r < 16; r++) {
            int o = (m0 + mt) * 32 + (r & 3) + 8 * (r >> 2) + 4 * g;
            float v = A[mt][r] + convb[o];
            yb[(size_t)o * N_] = v;
            float s = v, q = v * v;
#pragma unroll
            for (int d = 1; d < 32; d <<= 1) {
                s += __shfl_xor(s, d);
                q += __shfl_xor(q, d);
            }
            if (col == 0) {
                atomicAdd(&bns[o], s);
                atomicAdd(&bns[COUT_ + o], q);
            }
        }
}

// K5: y -> BN affine (stats derived inline from fused sums) -> exact GELU
__global__ __launch_bounds__(256) void bn_gelu_out(const float* __restrict__ y,
                                                   const float* __restrict__ bns,
                                                   const float* __restrict__ gamma,
                                                   const float* __restrict__ beta,
                                                   float* __restrict__ out) {
    const int total4 = (B_ * COUT_ * N_) / 4;
    int i = blockIdx.x * 256 + threadIdx.x;
    if (i >= total4) return;
    int base = i * 4;
    int o = (base / N_) % COUT_;
    const float invn = 1.0f / (float)NTOK_;
    float s = bns[o], q = bns[COUT_ + o];
    float mean = s * invn;
    float var  = q * invn - mean * mean;
    float sc   = gamma[o] * rsqrtf(var + BN_EPS);
    float sh   = beta[o] - mean * sc;
    float4 v = *(const float4*)&y[base];
    float u0 = fmaf(v.x, sc, sh), u1 = fmaf(v.y, sc, sh);
    float u2 = fmaf(v.z, sc, sh), u3 = fmaf(v.w, sc, sh);
    const float k = 0.70710678118654752f;
    float4 g;
    g.x = 0.5f * u0 * (1.0f + erff(u0 * k));
    g.y = 0.5f * u1 * (1.0f + erff(u1 * k));
    g.z = 0.5f * u2 * (1.0f + erff(u2 * k));
    g.w = 0.5f * u3 * (1.0f + erff(u3 * k));
    *(float4*)&out[base] = g;
}

// ---------------------------------------------------------------------------
extern "C" void kernel_launch(void* const* d_in, const int* in_sizes, int n_in,
                              void* d_out, int out_size, void* d_ws, size_t ws_size,
                              hipStream_t stream) {
    const float* x     = (const float*)d_in[0];
    const float* w     = (const float*)d_in[1];
    const float* cb    = (const float*)d_in[2];
    const float* gamma = (const float*)d_in[3];
    const float* beta  = (const float*)d_in[4];

    u16* xt_hi = (u16*)d_ws;                         // BNC bf16
    u16* xt_lo = xt_hi + (size_t)BNC;                // BNC
    u16* xc_hi = xt_lo + (size_t)BNC;                // BNC
    float* attT  = (float*)(xc_hi + (size_t)BNC);    // BNC fp32 (channel-major, unnormalized)
    u16* whi   = (u16*)(attT + (size_t)BNC);         // 192*192 bf16
    u16* wlo   = whi + COUT_ * 2 * C_;               // 192*192 bf16
    float* y     = (float*)(wlo + COUT_ * 2 * C_);   // B*COUT*N fp32
    float* bns   = y + (size_t)B_ * COUT_ * N_;      // 2*COUT (sum, sumsq)
    float* l_arr = bns + 2 * COUT_;                  // NTOK
    float* norm2 = l_arr + NTOK_;                    // NTOK
    int*   maxb  = (int*)(norm2 + NTOK_);            // 1

    hipMemsetAsync(l_arr, 0, NTOK_ * sizeof(float), stream);
    hipMemsetAsync(norm2, 0, NTOK_ * sizeof(float), stream);
    hipMemsetAsync(bns, 0, 2 * COUT_ * sizeof(float), stream);
    hipMemsetAsync(attT, 0, (size_t)BNC * sizeof(float), stream);

    transpose_split<<<dim3(N_ / 32, C_ / 32, B_), 256, 0, stream>>>(x, xt_hi, xt_lo, xc_hi, norm2);
    cast_w<<<dim3((COUT_ * 2 * C_ + 255) / 256), 256, 0, stream>>>(w, whi, wlo);
    norm_max<<<dim3(1), 256, 0, stream>>>(norm2, maxb);
    flash_attn_mfma32<<<dim3((N_ + 127) / 128, B_, NSPLIT), 256, 0, stream>>>(
        xt_hi, xt_lo, xc_hi, norm2, maxb, attT, l_arr);
    conv_mfma<<<dim3(B_ * (N_ / 32)), 128, 0, stream>>>(x, attT, l_arr, whi, wlo, cb, y, bns);
    bn_gelu_out<<<dim3((B_ * COUT_ * N_ / 4 + 255) / 256), 256, 0, stream>>>(y, bns, gamma, beta, (float*)d_out);
}

// Round 5
// 242.273 us; speedup vs baseline: 2.2412x; 2.2412x over previous
//
#include <hip/hip_runtime.h>
#include <hip/hip_bf16.h>

// Problem constants
#define B_    8
#define C_    96
#define N_    3136      // 56*56
#define COUT_ 192
#define NTOK_ 25088     // B_*N_
#define BN_EPS 1e-5f

#define CROW 200        // conv cat LDS token-row stride in bf16 (192+8): 400B = 25*16 odd -> conflict-free
#define BNC  (B_ * N_ * C_)
#define NSPLIT 4
#define NT98  98        // 32-row K tiles per batch (3136/32)

// K2 LDS geometry (bytes), per buffer:
//  Kh: 32 rows * 208B (13 chunks of 16B: 12 data + 1 pad; 13 odd -> bank-perm) = 6656, pad to 7*1024
//  Kl: same, at +7168
//  V : 96 ch * 80B (5 chunks: 4 data + 1 pad) = 7680, pad to 8*1024, at +14336
#define K2_KL_OFF 7168
#define K2_V_OFF  14336
#define K2_BUFSZ  22528

typedef __hip_bfloat16 bf16;
typedef unsigned short u16;
typedef unsigned int u32;
typedef __attribute__((ext_vector_type(8))) short short8;    // 8 bf16 = 16B (MFMA A/B frag)
typedef __attribute__((ext_vector_type(16))) float f32x16;   // 32x32 MFMA C/D frag

__device__ __forceinline__ u16 f2bf(float f) {
    union { __hip_bfloat16 h; u16 u; } cv;
    cv.h = __float2bfloat16(f);
    return cv.u;
}
__device__ __forceinline__ float bf2f(u16 v) {
    union { u16 u; __hip_bfloat16 h; } cv;
    cv.u = v;
    return __bfloat162float(cv.h);
}
__device__ __forceinline__ u32 packbf2(float lo, float hi) {
    return ((u32)f2bf(hi) << 16) | (u32)f2bf(lo);
}

// async global->LDS DMA, 16B per lane: LDS dest = WAVE-UNIFORM base + lane*16.
__device__ __forceinline__ void gload_lds16(const void* g, void* l) {
    __builtin_amdgcn_global_load_lds((const __attribute__((address_space(1))) void*)g,
                                     (__attribute__((address_space(3))) void*)l,
                                     16, 0, 0);
}

// ---------------------------------------------------------------------------
// K1: x [B][C][N] fp32 -> xt_hi/xt_lo [B][N][C] bf16 (token-major, hi/lo split)
//                         xc_hi [B][C][N] bf16 (channel-major, V staged from here)
// Fused: per-token squared-norm partial sums (32 channels per block) -> norm2.
__global__ __launch_bounds__(256) void transpose_split(const float* __restrict__ x,
                                                       u16* __restrict__ xt_hi,
                                                       u16* __restrict__ xt_lo,
                                                       u16* __restrict__ xc_hi,
                                                       float* __restrict__ norm2) {
    __shared__ float tile[32][33];
    __shared__ float nrm[32];
    const int nb = blockIdx.x * 32;
    const int cb = blockIdx.y * 32;
    const int b  = blockIdx.z;
    const int tid = threadIdx.x;
    const int tx = tid & 31;
    const int ty = tid >> 5;
    if (tid < 32) nrm[tid] = 0.0f;
    float psum = 0.0f;
#pragma unroll
    for (int r = 0; r < 32; r += 8) {
        size_t idx = ((size_t)b * C_ + cb + ty + r) * N_ + nb + tx;
        float v = x[idx];
        tile[ty + r][tx] = v;
        xc_hi[idx] = f2bf(v);
        psum = fmaf(v, v, psum);
    }
    __syncthreads();               // tile visible; nrm init done
    atomicAdd(&nrm[tx], psum);     // LDS atomic, 8 adders per slot
#pragma unroll
    for (int r = 0; r < 32; r += 8) {
        float v = tile[tx][ty + r];
        u16 h = f2bf(v);
        size_t o = ((size_t)b * N_ + nb + ty + r) * C_ + cb + tx;
        xt_hi[o] = h;
        xt_lo[o] = f2bf(v - bf2f(h));
    }
    __syncthreads();               // nrm complete
    if (tid < 32)
        atomicAdd(&norm2[(size_t)b * N_ + nb + tid], nrm[tid]);
}

// K1b: conv_w [O][2C] fp32 -> whi/wlo bf16 (same [o][c] layout, hi/lo split)
__global__ __launch_bounds__(256) void cast_w(const float* __restrict__ w,
                                              u16* __restrict__ whi,
                                              u16* __restrict__ wlo) {
    int i = blockIdx.x * 256 + threadIdx.x;
    if (i >= COUT_ * 2 * C_) return;
    float v = w[i];
    u16 h = f2bf(v);
    whi[i] = h;
    wlo[i] = f2bf(v - bf2f(h));
}

// K1c: global max of norm2 (single block)
__global__ __launch_bounds__(256) void norm_max(const float* __restrict__ norm2,
                                                int* __restrict__ maxbits) {
    const int tid = threadIdx.x;
    float m = 0.0f;
    for (int i = tid; i < NTOK_; i += 256) m = fmaxf(m, norm2[i]);
#pragma unroll
    for (int d = 1; d < 64; d <<= 1) m = fmaxf(m, __shfl_xor(m, d));
    __shared__ float wmax[4];
    if ((tid & 63) == 0) wmax[tid >> 6] = m;
    __syncthreads();
    if (tid == 0) {
        float mm = fmaxf(fmaxf(wmax[0], wmax[1]), fmaxf(wmax[2], wmax[3]));
        *maxbits = __float_as_int(mm);
    }
}

// ---------------------------------------------------------------------------
// K2: MFMA flash attention, transposed-S, 4-way split-K.
// R15 body (odd-stride LDS: K rows 208B = 13 granules, V rows 80B = 5 ->
// bank-permutation, conflict-free b128 reads). R16: unchanged; this round
// isolates its delta after the R15 conv/BN fusion regression is reverted.
__global__ __launch_bounds__(256, 3) void flash_attn_mfma32(const u16* __restrict__ xt_hi,
                                                            const u16* __restrict__ xt_lo,
                                                            const u16* __restrict__ xc_hi,
                                                            const float* __restrict__ norm2,
                                                            const int* __restrict__ maxbits,
                                                            float* __restrict__ attT,
                                                            float* __restrict__ l_arr) {
    __shared__ __align__(16) char LDSU[2][K2_BUFSZ];
    const int b     = blockIdx.y;
    const int i0    = blockIdx.x * 128;
    const int split = blockIdx.z;
    const int kt0   = (NT98 * split) / NSPLIT;
    const int kt1   = (NT98 * (split + 1)) / NSPLIT;
    const int tid   = threadIdx.x;
    const int lane  = tid & 63;
    const int w     = tid >> 6;
    const int col   = lane & 31;
    const int g     = lane >> 5;

    const u16* th = xt_hi + (size_t)b * N_ * C_;
    const u16* tl = xt_lo + (size_t)b * N_ * C_;
    const u16* vh = xc_hi + (size_t)b * C_ * N_;

    // Staging: 22 DMA slots of 1KB per buffer (Kh 0..6, Kl 7..13, V 14..21).
    // Wave w owns slots w+4j. Per-slot: wave-uniform LDS dest (HW adds
    // lane*16) + per-lane global source offset (tile term added at issue).
    u32 loff[6], dofs[6];
#pragma unroll
    for (int j = 0; j < 6; j++) {
        int s = w + 4 * j;
        if (s >= 22) { loff[j] = 0; dofs[j] = 0; continue; }
        if (s < 14) {                 // K hi/lo
            int kind = s < 7 ? 0 : 1;
            int t = s - kind * 7;
            int p = t * 64 + lane;    // physical 16B chunk 0..447
            int r = p / 13, c = p % 13;
            if (c > 11) c = 11;       // row pad chunk: duplicate read
            loff[j] = (r < 32) ? (u32)(r * 192 + c * 16) : 0u;   // tail pad
            dofs[j] = (u32)(kind * K2_KL_OFF + t * 1024);
        } else {                      // V
            int t = s - 14;
            int p = t * 64 + lane;    // 0..511
            int ch = p / 5, c = p % 5;
            if (c > 3) c = 3;
            loff[j] = (ch < 96) ? (u32)(ch * (N_ * 2) + c * 16) : 0u;
            dofs[j] = (u32)(K2_V_OFF + t * 1024);
        }
    }

    // Q B-frags from global, once (lane holds its own q-row)
    const int qrow  = i0 + w * 32 + col;
    const int qrowc = qrow < N_ ? qrow : N_ - 1;
    short8 qh[6], ql[6];
#pragma unroll
    for (int kc = 0; kc < 6; kc++) {
        qh[kc] = *(const short8*)&th[(size_t)qrowc * C_ + kc * 16 + g * 8];
        ql[kc] = *(const short8*)&tl[(size_t)qrowc * C_ + kc * 16 + g * 8];
    }
    const float maxn2 = __int_as_float(*maxbits);
    const float m_i   = sqrtf(norm2[(size_t)b * N_ + qrowc] * maxn2);
    float l_acc = 0.0f;
    f32x16 O0 = {0}, O1 = {0}, O2 = {0};

    // stage tile kt into buffer nbuf (async DMA; drained at next barrier)
    auto stage = [&](int nbuf, int kt) {
        const u32 ktK = (u32)kt * 6144u;   // 32 rows * 192B
        const u32 ktV = (u32)kt * 64u;     // 32 tokens * 2B
#pragma unroll
        for (int j = 0; j < 6; j++) {
            int s = w + 4 * j;
            if (s >= 22) break;
            const char* sb = (s < 7)  ? (const char*)th + ktK
                           : (s < 14) ? (const char*)tl + ktK
                                      : (const char*)vh + ktV;
            gload_lds16(sb + loff[j], (char*)&LDSU[nbuf][0] + dofs[j]);
        }
    };

    stage(0, kt0);
    __syncthreads();

    const int g16 = g * 16;
    int buf = 0;
    for (int kt = kt0; kt < kt1; kt++) {
        // (1) prefetch next tile into back buffer (in flight across compute)
        if (kt + 1 < kt1) stage(buf ^ 1, kt + 1);

        const char* Lb = (const char*)&LDSU[buf][0];

        // (2) QK^T: S[k=0..31][q=col], hi/lo split (3 MFMA per k-chunk)
        f32x16 S = {0};
        __builtin_amdgcn_s_setprio(1);
#pragma unroll
        for (int kc = 0; kc < 6; kc++) {
            const int o2 = col * 208 + kc * 32 + g16;
            short8 kh = *(const short8*)(Lb + o2);
            short8 kl = *(const short8*)(Lb + K2_KL_OFF + o2);
            S = __builtin_amdgcn_mfma_f32_32x32x16_bf16(kh, ql[kc], S, 0, 0, 0);
            S = __builtin_amdgcn_mfma_f32_32x32x16_bf16(kl, qh[kc], S, 0, 0, 0);
            S = __builtin_amdgcn_mfma_f32_32x32x16_bf16(kh, qh[kc], S, 0, 0, 0);
        }
        __builtin_amdgcn_s_setprio(0);

        // (3) softmax numerators + bf16 pack
        float p[16];
#pragma unroll
        for (int r = 0; r < 16; r++) {
            p[r] = __expf(S[r] - m_i);
            l_acc += p[r];
        }
        u32 w8[8];
#pragma unroll
        for (int q = 0; q < 8; q++) w8[q] = packbf2(p[2 * q], p[2 * q + 1]);

        // (4) PV from V-LDS (rows 80B: conflict-free)
        __builtin_amdgcn_s_setprio(1);
#pragma unroll
        for (int kc = 0; kc < 2; kc++) {
            const int qb = kc * 4;
            u32 a0 = w8[qb + 0], a1 = w8[qb + 1];
            u32 a2 = w8[qb + 2], a3 = w8[qb + 3];
            u32 s0 = __shfl_xor((int)a0, 32), s1 = __shfl_xor((int)a1, 32);
            u32 s2 = __shfl_xor((int)a2, 32), s3 = __shfl_xor((int)a3, 32);
            union { short8 v; u32 u[4]; } Bf;
            Bf.u[0] = g ? s2 : a0;
            Bf.u[1] = g ? s3 : a1;
            Bf.u[2] = g ? a2 : s0;
            Bf.u[3] = g ? a3 : s1;
            const int vo = K2_V_OFF + col * 80 + kc * 32 + g16;
            short8 v0 = *(const short8*)(Lb + vo);
            short8 v1 = *(const short8*)(Lb + vo + 2560);   // +32 ch * 80B
            short8 v2 = *(const short8*)(Lb + vo + 5120);   // +64 ch * 80B
            O0 = __builtin_amdgcn_mfma_f32_32x32x16_bf16(v0, Bf.v, O0, 0, 0, 0);
            O1 = __builtin_amdgcn_mfma_f32_32x32x16_bf16(v1, Bf.v, O1, 0, 0, 0);
            O2 = __builtin_amdgcn_mfma_f32_32x32x16_bf16(v2, Bf.v, O2, 0, 0, 0);
        }
        __builtin_amdgcn_s_setprio(0);

        __syncthreads();     // drains my DMAs + all waves' LDS reads done
        buf ^= 1;
    }

    if (qrow < N_) {
        float* ab = attT + (size_t)b * C_ * N_ + qrow;
#pragma unroll
        for (int r = 0; r < 16; r++) {
            int c = (r & 3) + 8 * (r >> 2) + 4 * g;
            atomicAdd(&ab[(size_t)(c)      * N_], O0[r]);
            atomicAdd(&ab[(size_t)(c + 32) * N_], O1[r]);
            atomicAdd(&ab[(size_t)(c + 64) * N_], O2[r]);
        }
        float l_tot = l_acc + __shfl_xor(l_acc, 32);
        if (g == 0) atomicAdd(&l_arr[(size_t)b * N_ + qrow], l_tot);
    }
}

// ---------------------------------------------------------------------------
// K3: MFMA 1x1 conv — Round-3 version restored EXACTLY (R15's fused-BN
// epilogue was ~300K same-line device atomics -> 340us serialization).
__global__ __launch_bounds__(256, 3) void conv_mfma(const float* __restrict__ x,
                                                    const float* __restrict__ attT,
                                                    const float* __restrict__ l_arr,
                                                    const u16* __restrict__ whi,
                                                    const u16* __restrict__ wlo,
                                                    const float* __restrict__ convb,
                                                    float* __restrict__ y) {
    __shared__ u16 ch[64 * CROW];
    __shared__ u16 cl[64 * CROW];
    __shared__ float invl[64];
    const int b   = blockIdx.x / (N_ / 64);
    const int n0  = (blockIdx.x % (N_ / 64)) * 64;
    const int tid = threadIdx.x;

    if (tid < 64) invl[tid] = 1.0f / l_arr[(size_t)b * N_ + n0 + tid];
    __syncthreads();

    const float* xb = x    + (size_t)b * C_ * N_ + n0;
    const float* ab = attT + (size_t)b * C_ * N_ + n0;
    for (int e = tid; e < 64 * C_; e += 256) {
        int c = e >> 6, t = e & 63;
        float xv = xb[(size_t)c * N_ + t];
        float au = ab[(size_t)c * N_ + t];
        float xj = fmaxf(xv - au * invl[t], 0.0f);
        u16 h1 = f2bf(xv);
        ch[t * CROW + c] = h1;
        cl[t * CROW + c] = f2bf(xv - bf2f(h1));
        u16 h2 = f2bf(xj);
        ch[t * CROW + C_ + c] = h2;
        cl[t * CROW + C_ + c] = f2bf(xj - bf2f(h2));
    }
    __syncthreads();

    const int lane = tid & 63;
    const int w    = tid >> 6;
    const int col  = lane & 31;
    const int g    = lane >> 5;
    const int nt   = w & 1;
    const int m0   = (w >> 1) * 3;

    f32x16 A[3] = {{0}, {0}, {0}};
#pragma unroll
    for (int ks = 0; ks < 12; ks++) {
        const int k0 = ks * 16;
        short8 bh = *(const short8*)&ch[(nt * 32 + col) * CROW + k0 + g * 8];
        short8 bl = *(const short8*)&cl[(nt * 32 + col) * CROW + k0 + g * 8];
#pragma unroll
        for (int mt = 0; mt < 3; mt++) {
            const size_t wo = (size_t)((m0 + mt) * 32 + col) * (2 * C_) + k0 + g * 8;
            short8 ah = *(const short8*)&whi[wo];
            short8 al = *(const short8*)&wlo[wo];
            A[mt] = __builtin_amdgcn_mfma_f32_32x32x16_bf16(ah, bl, A[mt], 0, 0, 0);
            A[mt] = __builtin_amdgcn_mfma_f32_32x32x16_bf16(al, bh, A[mt], 0, 0, 0);
            A[mt] = __builtin_amdgcn_mfma_f32_32x32x16_bf16(ah, bh, A[mt], 0, 0, 0);
        }
    }

    float* yb = y + (size_t)b * COUT_ * N_ + n0 + nt * 32 + col;
#pragma unroll
    for (int mt = 0; mt < 3; mt++)
#pragma unroll
        for (int r = 0; r < 16; r++) {
            int o = (m0 + mt) * 32 + (r & 3) + 8 * (r >> 2) + 4 * g;
            yb[(size_t)o * N_] = A[mt][r] + convb[o];
        }
}

// ---------------------------------------------------------------------------
// K4: per-channel BN stats from y -> scale/shift (one block per channel)
__global__ __launch_bounds__(256) void bn_stats(const float* __restrict__ y,
                                                const float* __restrict__ gamma,
                                                const float* __restrict__ beta,
                                                float* __restrict__ ss) {
    const int o   = blockIdx.x;
    const int tid = threadIdx.x;
    float s = 0.0f, q = 0.0f;
#pragma unroll
    for (int b = 0; b < B_; b++) {
        const float4* p = (const float4*)(y + (size_t)(b * COUT_ + o) * N_);
        for (int i = tid; i < N_ / 4; i += 256) {
            float4 v = p[i];
            s += v.x + v.y + v.z + v.w;
            q += v.x * v.x + v.y * v.y + v.z * v.z + v.w * v.w;
        }
    }
#pragma unroll
    for (int d = 1; d < 64; d <<= 1) {
        s += __shfl_xor(s, d);
        q += __shfl_xor(q, d);
    }
    __shared__ float wss[4], wqq[4];
    if ((tid & 63) == 0) { wss[tid >> 6] = s; wqq[tid >> 6] = q; }
    __syncthreads();
    if (tid == 0) {
        float st = wss[0] + wss[1] + wss[2] + wss[3];
        float qt = wqq[0] + wqq[1] + wqq[2] + wqq[3];
        const float invn = 1.0f / (float)NTOK_;
        float mean = st * invn;
        float var  = qt * invn - mean * mean;
        float sc   = gamma[o] * rsqrtf(var + BN_EPS);
        ss[o]         = sc;
        ss[COUT_ + o] = beta[o] - mean * sc;
    }
}

// K5: y -> BN affine -> exact GELU -> fp32 out
__global__ __launch_bounds__(256) void bn_gelu_out(const float* __restrict__ y,
                                                   const float* __restrict__ ss,
                                                   float* __restrict__ out) {
    const int total4 = (B_ * COUT_ * N_) / 4;
    int i = blockIdx.x * 256 + threadIdx.x;
    if (i >= total4) return;
    int base = i * 4;
    int o = (base / N_) % COUT_;
    float sc = ss[o], sh = ss[COUT_ + o];
    float4 v = *(const float4*)&y[base];
    float u0 = fmaf(v.x, sc, sh), u1 = fmaf(v.y, sc, sh);
    float u2 = fmaf(v.z, sc, sh), u3 = fmaf(v.w, sc, sh);
    const float k = 0.70710678118654752f;
    float4 g;
    g.x = 0.5f * u0 * (1.0f + erff(u0 * k));
    g.y = 0.5f * u1 * (1.0f + erff(u1 * k));
    g.z = 0.5f * u2 * (1.0f + erff(u2 * k));
    g.w = 0.5f * u3 * (1.0f + erff(u3 * k));
    *(float4*)&out[base] = g;
}

// ---------------------------------------------------------------------------
extern "C" void kernel_launch(void* const* d_in, const int* in_sizes, int n_in,
                              void* d_out, int out_size, void* d_ws, size_t ws_size,
                              hipStream_t stream) {
    const float* x     = (const float*)d_in[0];
    const float* w     = (const float*)d_in[1];
    const float* cb    = (const float*)d_in[2];
    const float* gamma = (const float*)d_in[3];
    const float* beta  = (const float*)d_in[4];

    u16* xt_hi = (u16*)d_ws;                         // BNC bf16
    u16* xt_lo = xt_hi + (size_t)BNC;                // BNC
    u16* xc_hi = xt_lo + (size_t)BNC;                // BNC
    float* attT  = (float*)(xc_hi + (size_t)BNC);    // BNC fp32 (channel-major, unnormalized)
    u16* whi   = (u16*)(attT + (size_t)BNC);         // 192*192 bf16
    u16* wlo   = whi + COUT_ * 2 * C_;               // 192*192 bf16
    float* y     = (float*)(wlo + COUT_ * 2 * C_);   // B*COUT*N fp32
    float* ss    = y + (size_t)B_ * COUT_ * N_;      // 2*COUT
    float* l_arr = ss + 2 * COUT_;                   // NTOK
    float* norm2 = l_arr + NTOK_;                    // NTOK
    int*   maxb  = (int*)(norm2 + NTOK_);            // 1

    hipMemsetAsync(l_arr, 0, NTOK_ * sizeof(float), stream);
    hipMemsetAsync(norm2, 0, NTOK_ * sizeof(float), stream);
    hipMemsetAsync(attT, 0, (size_t)BNC * sizeof(float), stream);

    transpose_split<<<dim3(N_ / 32, C_ / 32, B_), 256, 0, stream>>>(x, xt_hi, xt_lo, xc_hi, norm2);
    cast_w<<<dim3((COUT_ * 2 * C_ + 255) / 256), 256, 0, stream>>>(w, whi, wlo);
    norm_max<<<dim3(1), 256, 0, stream>>>(norm2, maxb);
    flash_attn_mfma32<<<dim3((N_ + 127) / 128, B_, NSPLIT), 256, 0, stream>>>(
        xt_hi, xt_lo, xc_hi, norm2, maxb, attT, l_arr);
    conv_mfma<<<dim3(B_ * (N_ / 64)), 256, 0, stream>>>(x, attT, l_arr, whi, wlo, cb, y);
    bn_stats<<<dim3(COUT_), 256, 0, stream>>>(y, gamma, beta, ss);
    bn_gelu_out<<<dim3((B_ * COUT_ * N_ / 4 + 255) / 256), 256, 0, stream>>>(y, ss, (float*)d_out);
}

// Round 6
// 238.388 us; speedup vs baseline: 2.2777x; 1.0163x over previous
//
#include <hip/hip_runtime.h>
#include <hip/hip_bf16.h>

// Problem constants
#define B_    8
#define C_    96
#define N_    3136      // 56*56
#define COUT_ 192
#define NTOK_ 25088     // B_*N_
#define BN_EPS 1e-5f

#define CROW 200        // conv cat LDS token-row stride in bf16 (192+8): 400B = 25*16 odd -> conflict-free
#define BNC  (B_ * N_ * C_)
#define NSPLIT 4
#define NT98  98        // 32-row K tiles per batch (3136/32)

// K2 LDS geometry (bytes), per buffer:
//  Kh: 32 rows * 208B (13 chunks of 16B: 12 data + 1 pad; 13 odd -> bank-perm) = 6656, pad to 7*1024
//  Kl: same, at +7168
//  V : 96 ch * 80B (5 chunks: 4 data + 1 pad) = 7680, pad to 8*1024, at +14336
#define K2_KL_OFF 7168
#define K2_V_OFF  14336
#define K2_BUFSZ  22528

typedef __hip_bfloat16 bf16;
typedef unsigned short u16;
typedef unsigned int u32;
typedef __attribute__((ext_vector_type(8))) short short8;    // 8 bf16 = 16B (MFMA A/B frag)
typedef __attribute__((ext_vector_type(16))) float f32x16;   // 32x32 MFMA C/D frag

__device__ __forceinline__ u16 f2bf(float f) {
    union { __hip_bfloat16 h; u16 u; } cv;
    cv.h = __float2bfloat16(f);
    return cv.u;
}
__device__ __forceinline__ float bf2f(u16 v) {
    union { u16 u; __hip_bfloat16 h; } cv;
    cv.u = v;
    return __bfloat162float(cv.h);
}
__device__ __forceinline__ u32 packbf2(float lo, float hi) {
    return ((u32)f2bf(hi) << 16) | (u32)f2bf(lo);
}

// async global->LDS DMA, 16B per lane: LDS dest = WAVE-UNIFORM base + lane*16.
__device__ __forceinline__ void gload_lds16(const void* g, void* l) {
    __builtin_amdgcn_global_load_lds((const __attribute__((address_space(1))) void*)g,
                                     (__attribute__((address_space(3))) void*)l,
                                     16, 0, 0);
}

// ---------------------------------------------------------------------------
// K1: x [B][C][N] fp32 -> xt_hi/xt_lo [B][N][C] bf16 (token-major, hi/lo split)
//                         xc_hi [B][C][N] bf16 (channel-major, V staged from here)
// Fused: per-token squared-norm partial sums (32 channels per block) -> norm2.
// R17: phase-2 writes vectorized (channel-pair u32 stores, 4B/lane).
__global__ __launch_bounds__(256) void transpose_split(const float* __restrict__ x,
                                                       u16* __restrict__ xt_hi,
                                                       u16* __restrict__ xt_lo,
                                                       u16* __restrict__ xc_hi,
                                                       float* __restrict__ norm2) {
    __shared__ float tile[32][33];
    __shared__ float nrm[32];
    const int nb = blockIdx.x * 32;
    const int cb = blockIdx.y * 32;
    const int b  = blockIdx.z;
    const int tid = threadIdx.x;
    const int tx = tid & 31;
    const int ty = tid >> 5;
    if (tid < 32) nrm[tid] = 0.0f;
    float psum = 0.0f;
#pragma unroll
    for (int r = 0; r < 32; r += 8) {
        size_t idx = ((size_t)b * C_ + cb + ty + r) * N_ + nb + tx;
        float v = x[idx];
        tile[ty + r][tx] = v;
        xc_hi[idx] = f2bf(v);
        psum = fmaf(v, v, psum);
    }
    __syncthreads();               // tile visible; nrm init done
    atomicAdd(&nrm[tx], psum);     // LDS atomic, 8 adders per slot
    // phase 2: token-major hi/lo writes, 2 channels per thread as one u32
#pragma unroll
    for (int it = 0; it < 4; it++) {
        const int n2 = (tid >> 4) + it * 16;   // token 0..31 within tile... (256 thr: tid>>4 in 0..15)
        const int cp = tid & 15;               // channel pair 0..15
        float v0 = tile[2 * cp][n2];
        float v1 = tile[2 * cp + 1][n2];
        u16 h0 = f2bf(v0), h1 = f2bf(v1);
        u16 l0 = f2bf(v0 - bf2f(h0)), l1 = f2bf(v1 - bf2f(h1));
        size_t o = ((size_t)b * N_ + nb + n2) * C_ + cb + 2 * cp;
        *(u32*)&xt_hi[o] = (u32)h0 | ((u32)h1 << 16);
        *(u32*)&xt_lo[o] = (u32)l0 | ((u32)l1 << 16);
        if (it == 1) break;        // 256 threads * 2 iters cover 32x16 pairs
    }
    __syncthreads();               // nrm complete
    if (tid < 32)
        atomicAdd(&norm2[(size_t)b * N_ + nb + tid], nrm[tid]);
}

// K1b: conv_w [O][2C] fp32 -> whi/wlo bf16 (same [o][c] layout, hi/lo split)
__global__ __launch_bounds__(256) void cast_w(const float* __restrict__ w,
                                              u16* __restrict__ whi,
                                              u16* __restrict__ wlo) {
    int i = blockIdx.x * 256 + threadIdx.x;
    if (i >= COUT_ * 2 * C_) return;
    float v = w[i];
    u16 h = f2bf(v);
    whi[i] = h;
    wlo[i] = f2bf(v - bf2f(h));
}

// K1c: global max of norm2 (single block)
__global__ __launch_bounds__(256) void norm_max(const float* __restrict__ norm2,
                                                int* __restrict__ maxbits) {
    const int tid = threadIdx.x;
    float m = 0.0f;
    for (int i = tid; i < NTOK_; i += 256) m = fmaxf(m, norm2[i]);
#pragma unroll
    for (int d = 1; d < 64; d <<= 1) m = fmaxf(m, __shfl_xor(m, d));
    __shared__ float wmax[4];
    if ((tid & 63) == 0) wmax[tid >> 6] = m;
    __syncthreads();
    if (tid == 0) {
        float mm = fmaxf(fmaxf(wmax[0], wmax[1]), fmaxf(wmax[2], wmax[3]));
        *maxbits = __float_as_int(mm);
    }
}

// ---------------------------------------------------------------------------
// K2: MFMA flash attention, transposed-S, 4-way split-K.
// R15 odd-stride LDS verified in R16: SQ_LDS_BANK_CONFLICT 16.9M -> 0,
// dur 115 -> 102us. R17: UNTOUCHED (control while non-K2 side changes).
__global__ __launch_bounds__(256, 3) void flash_attn_mfma32(const u16* __restrict__ xt_hi,
                                                            const u16* __restrict__ xt_lo,
                                                            const u16* __restrict__ xc_hi,
                                                            const float* __restrict__ norm2,
                                                            const int* __restrict__ maxbits,
                                                            float* __restrict__ attT,
                                                            float* __restrict__ l_arr) {
    __shared__ __align__(16) char LDSU[2][K2_BUFSZ];
    const int b     = blockIdx.y;
    const int i0    = blockIdx.x * 128;
    const int split = blockIdx.z;
    const int kt0   = (NT98 * split) / NSPLIT;
    const int kt1   = (NT98 * (split + 1)) / NSPLIT;
    const int tid   = threadIdx.x;
    const int lane  = tid & 63;
    const int w     = tid >> 6;
    const int col   = lane & 31;
    const int g     = lane >> 5;

    const u16* th = xt_hi + (size_t)b * N_ * C_;
    const u16* tl = xt_lo + (size_t)b * N_ * C_;
    const u16* vh = xc_hi + (size_t)b * C_ * N_;

    u32 loff[6], dofs[6];
#pragma unroll
    for (int j = 0; j < 6; j++) {
        int s = w + 4 * j;
        if (s >= 22) { loff[j] = 0; dofs[j] = 0; continue; }
        if (s < 14) {                 // K hi/lo
            int kind = s < 7 ? 0 : 1;
            int t = s - kind * 7;
            int p = t * 64 + lane;    // physical 16B chunk 0..447
            int r = p / 13, c = p % 13;
            if (c > 11) c = 11;       // row pad chunk: duplicate read
            loff[j] = (r < 32) ? (u32)(r * 192 + c * 16) : 0u;   // tail pad
            dofs[j] = (u32)(kind * K2_KL_OFF + t * 1024);
        } else {                      // V
            int t = s - 14;
            int p = t * 64 + lane;    // 0..511
            int ch = p / 5, c = p % 5;
            if (c > 3) c = 3;
            loff[j] = (ch < 96) ? (u32)(ch * (N_ * 2) + c * 16) : 0u;
            dofs[j] = (u32)(K2_V_OFF + t * 1024);
        }
    }

    // Q B-frags from global, once (lane holds its own q-row)
    const int qrow  = i0 + w * 32 + col;
    const int qrowc = qrow < N_ ? qrow : N_ - 1;
    short8 qh[6], ql[6];
#pragma unroll
    for (int kc = 0; kc < 6; kc++) {
        qh[kc] = *(const short8*)&th[(size_t)qrowc * C_ + kc * 16 + g * 8];
        ql[kc] = *(const short8*)&tl[(size_t)qrowc * C_ + kc * 16 + g * 8];
    }
    const float maxn2 = __int_as_float(*maxbits);
    const float m_i   = sqrtf(norm2[(size_t)b * N_ + qrowc] * maxn2);
    float l_acc = 0.0f;
    f32x16 O0 = {0}, O1 = {0}, O2 = {0};

    // stage tile kt into buffer nbuf (async DMA; drained at next barrier)
    auto stage = [&](int nbuf, int kt) {
        const u32 ktK = (u32)kt * 6144u;   // 32 rows * 192B
        const u32 ktV = (u32)kt * 64u;     // 32 tokens * 2B
#pragma unroll
        for (int j = 0; j < 6; j++) {
            int s = w + 4 * j;
            if (s >= 22) break;
            const char* sb = (s < 7)  ? (const char*)th + ktK
                           : (s < 14) ? (const char*)tl + ktK
                                      : (const char*)vh + ktV;
            gload_lds16(sb + loff[j], (char*)&LDSU[nbuf][0] + dofs[j]);
        }
    };

    stage(0, kt0);
    __syncthreads();

    const int g16 = g * 16;
    int buf = 0;
    for (int kt = kt0; kt < kt1; kt++) {
        // (1) prefetch next tile into back buffer (in flight across compute)
        if (kt + 1 < kt1) stage(buf ^ 1, kt + 1);

        const char* Lb = (const char*)&LDSU[buf][0];

        // (2) QK^T: S[k=0..31][q=col], hi/lo split (3 MFMA per k-chunk)
        f32x16 S = {0};
        __builtin_amdgcn_s_setprio(1);
#pragma unroll
        for (int kc = 0; kc < 6; kc++) {
            const int o2 = col * 208 + kc * 32 + g16;
            short8 kh = *(const short8*)(Lb + o2);
            short8 kl = *(const short8*)(Lb + K2_KL_OFF + o2);
            S = __builtin_amdgcn_mfma_f32_32x32x16_bf16(kh, ql[kc], S, 0, 0, 0);
            S = __builtin_amdgcn_mfma_f32_32x32x16_bf16(kl, qh[kc], S, 0, 0, 0);
            S = __builtin_amdgcn_mfma_f32_32x32x16_bf16(kh, qh[kc], S, 0, 0, 0);
        }
        __builtin_amdgcn_s_setprio(0);

        // (3) softmax numerators + bf16 pack
        float p[16];
#pragma unroll
        for (int r = 0; r < 16; r++) {
            p[r] = __expf(S[r] - m_i);
            l_acc += p[r];
        }
        u32 w8[8];
#pragma unroll
        for (int q = 0; q < 8; q++) w8[q] = packbf2(p[2 * q], p[2 * q + 1]);

        // (4) PV from V-LDS (rows 80B: conflict-free)
        __builtin_amdgcn_s_setprio(1);
#pragma unroll
        for (int kc = 0; kc < 2; kc++) {
            const int qb = kc * 4;
            u32 a0 = w8[qb + 0], a1 = w8[qb + 1];
            u32 a2 = w8[qb + 2], a3 = w8[qb + 3];
            u32 s0 = __shfl_xor((int)a0, 32), s1 = __shfl_xor((int)a1, 32);
            u32 s2 = __shfl_xor((int)a2, 32), s3 = __shfl_xor((int)a3, 32);
            union { short8 v; u32 u[4]; } Bf;
            Bf.u[0] = g ? s2 : a0;
            Bf.u[1] = g ? s3 : a1;
            Bf.u[2] = g ? a2 : s0;
            Bf.u[3] = g ? a3 : s1;
            const int vo = K2_V_OFF + col * 80 + kc * 32 + g16;
            short8 v0 = *(const short8*)(Lb + vo);
            short8 v1 = *(const short8*)(Lb + vo + 2560);   // +32 ch * 80B
            short8 v2 = *(const short8*)(Lb + vo + 5120);   // +64 ch * 80B
            O0 = __builtin_amdgcn_mfma_f32_32x32x16_bf16(v0, Bf.v, O0, 0, 0, 0);
            O1 = __builtin_amdgcn_mfma_f32_32x32x16_bf16(v1, Bf.v, O1, 0, 0, 0);
            O2 = __builtin_amdgcn_mfma_f32_32x32x16_bf16(v2, Bf.v, O2, 0, 0, 0);
        }
        __builtin_amdgcn_s_setprio(0);

        __syncthreads();     // drains my DMAs + all waves' LDS reads done
        buf ^= 1;
    }

    if (qrow < N_) {
        float* ab = attT + (size_t)b * C_ * N_ + qrow;
#pragma unroll
        for (int r = 0; r < 16; r++) {
            int c = (r & 3) + 8 * (r >> 2) + 4 * g;
            atomicAdd(&ab[(size_t)(c)      * N_], O0[r]);
            atomicAdd(&ab[(size_t)(c + 32) * N_], O1[r]);
            atomicAdd(&ab[(size_t)(c + 64) * N_], O2[r]);
        }
        float l_tot = l_acc + __shfl_xor(l_acc, 32);
        if (g == 0) atomicAdd(&l_arr[(size_t)b * N_ + qrow], l_tot);
    }
}

// ---------------------------------------------------------------------------
// K3: MFMA 1x1 conv. R17: 32-token/128-thread tiles (R15 geometry, verified
// correct there; WITHOUT the fatal same-line BN atomics). 784 blocks for
// better CU balance + shorter per-block staging chain.
__global__ __launch_bounds__(128, 3) void conv_mfma(const float* __restrict__ x,
                                                    const float* __restrict__ attT,
                                                    const float* __restrict__ l_arr,
                                                    const u16* __restrict__ whi,
                                                    const u16* __restrict__ wlo,
                                                    const float* __restrict__ convb,
                                                    float* __restrict__ y) {
    __shared__ u16 ch[32 * CROW];
    __shared__ u16 cl[32 * CROW];
    __shared__ float invl[32];
    const int b   = blockIdx.x / (N_ / 32);
    const int n0  = (blockIdx.x % (N_ / 32)) * 32;
    const int tid = threadIdx.x;

    if (tid < 32) invl[tid] = 1.0f / l_arr[(size_t)b * N_ + n0 + tid];
    __syncthreads();

    const float* xb = x    + (size_t)b * C_ * N_ + n0;
    const float* ab = attT + (size_t)b * C_ * N_ + n0;
    for (int e = tid; e < 32 * C_; e += 128) {
        int c = e >> 5, t = e & 31;
        float xv = xb[(size_t)c * N_ + t];
        float au = ab[(size_t)c * N_ + t];
        float xj = fmaxf(xv - au * invl[t], 0.0f);
        u16 h1 = f2bf(xv);
        ch[t * CROW + c] = h1;
        cl[t * CROW + c] = f2bf(xv - bf2f(h1));
        u16 h2 = f2bf(xj);
        ch[t * CROW + C_ + c] = h2;
        cl[t * CROW + C_ + c] = f2bf(xj - bf2f(h2));
    }
    __syncthreads();

    const int lane = tid & 63;
    const int w    = tid >> 6;        // 0..1
    const int col  = lane & 31;       // token within tile
    const int g    = lane >> 5;
    const int m0   = w * 3;           // wave's 3 m-tiles (96 channels)

    f32x16 A[3] = {{0}, {0}, {0}};
#pragma unroll
    for (int ks = 0; ks < 12; ks++) {
        const int k0 = ks * 16;
        short8 bh = *(const short8*)&ch[col * CROW + k0 + g * 8];
        short8 bl = *(const short8*)&cl[col * CROW + k0 + g * 8];
#pragma unroll
        for (int mt = 0; mt < 3; mt++) {
            const size_t wo = (size_t)((m0 + mt) * 32 + col) * (2 * C_) + k0 + g * 8;
            short8 ah = *(const short8*)&whi[wo];
            short8 al = *(const short8*)&wlo[wo];
            A[mt] = __builtin_amdgcn_mfma_f32_32x32x16_bf16(ah, bl, A[mt], 0, 0, 0);
            A[mt] = __builtin_amdgcn_mfma_f32_32x32x16_bf16(al, bh, A[mt], 0, 0, 0);
            A[mt] = __builtin_amdgcn_mfma_f32_32x32x16_bf16(ah, bh, A[mt], 0, 0, 0);
        }
    }

    float* yb = y + (size_t)b * COUT_ * N_ + n0 + col;
#pragma unroll
    for (int mt = 0; mt < 3; mt++)
#pragma unroll
        for (int r = 0; r < 16; r++) {
            int o = (m0 + mt) * 32 + (r & 3) + 8 * (r >> 2) + 4 * g;
            yb[(size_t)o * N_] = A[mt][r] + convb[o];
        }
}

// ---------------------------------------------------------------------------
// K4a: per-(b,channel) partial BN sums (distinct output lines, no contention)
__global__ __launch_bounds__(256) void bn_partial(const float* __restrict__ y,
                                                  float* __restrict__ pb) {
    const int o   = blockIdx.x;
    const int b   = blockIdx.y;
    const int tid = threadIdx.x;
    float s = 0.0f, q = 0.0f;
    const float4* p = (const float4*)(y + (size_t)(b * COUT_ + o) * N_);
    for (int i = tid; i < N_ / 4; i += 256) {
        float4 v = p[i];
        s += v.x + v.y + v.z + v.w;
        q += v.x * v.x + v.y * v.y + v.z * v.z + v.w * v.w;
    }
#pragma unroll
    for (int d = 1; d < 64; d <<= 1) {
        s += __shfl_xor(s, d);
        q += __shfl_xor(q, d);
    }
    __shared__ float wss[4], wqq[4];
    if ((tid & 63) == 0) { wss[tid >> 6] = s; wqq[tid >> 6] = q; }
    __syncthreads();
    if (tid == 0) {
        pb[b * COUT_ + o]                = wss[0] + wss[1] + wss[2] + wss[3];
        pb[B_ * COUT_ + b * COUT_ + o]   = wqq[0] + wqq[1] + wqq[2] + wqq[3];
    }
}

// K4b: reduce partials -> scale/shift
__global__ __launch_bounds__(192) void bn_finish(const float* __restrict__ pb,
                                                 const float* __restrict__ gamma,
                                                 const float* __restrict__ beta,
                                                 float* __restrict__ ss) {
    const int o = threadIdx.x;
    float s = 0.0f, q = 0.0f;
#pragma unroll
    for (int b = 0; b < B_; b++) {
        s += pb[b * COUT_ + o];
        q += pb[B_ * COUT_ + b * COUT_ + o];
    }
    const float invn = 1.0f / (float)NTOK_;
    float mean = s * invn;
    float var  = q * invn - mean * mean;
    float sc   = gamma[o] * rsqrtf(var + BN_EPS);
    ss[o]         = sc;
    ss[COUT_ + o] = beta[o] - mean * sc;
}

// K5: y -> BN affine -> exact GELU -> fp32 out
__global__ __launch_bounds__(256) void bn_gelu_out(const float* __restrict__ y,
                                                   const float* __restrict__ ss,
                                                   float* __restrict__ out) {
    const int total4 = (B_ * COUT_ * N_) / 4;
    int i = blockIdx.x * 256 + threadIdx.x;
    if (i >= total4) return;
    int base = i * 4;
    int o = (base / N_) % COUT_;
    float sc = ss[o], sh = ss[COUT_ + o];
    float4 v = *(const float4*)&y[base];
    float u0 = fmaf(v.x, sc, sh), u1 = fmaf(v.y, sc, sh);
    float u2 = fmaf(v.z, sc, sh), u3 = fmaf(v.w, sc, sh);
    const float k = 0.70710678118654752f;
    float4 g;
    g.x = 0.5f * u0 * (1.0f + erff(u0 * k));
    g.y = 0.5f * u1 * (1.0f + erff(u1 * k));
    g.z = 0.5f * u2 * (1.0f + erff(u2 * k));
    g.w = 0.5f * u3 * (1.0f + erff(u3 * k));
    *(float4*)&out[base] = g;
}

// ---------------------------------------------------------------------------
extern "C" void kernel_launch(void* const* d_in, const int* in_sizes, int n_in,
                              void* d_out, int out_size, void* d_ws, size_t ws_size,
                              hipStream_t stream) {
    const float* x     = (const float*)d_in[0];
    const float* w     = (const float*)d_in[1];
    const float* cb    = (const float*)d_in[2];
    const float* gamma = (const float*)d_in[3];
    const float* beta  = (const float*)d_in[4];

    u16* xt_hi = (u16*)d_ws;                         // BNC bf16
    u16* xt_lo = xt_hi + (size_t)BNC;                // BNC
    u16* xc_hi = xt_lo + (size_t)BNC;                // BNC
    float* attT  = (float*)(xc_hi + (size_t)BNC);    // BNC fp32 (channel-major, unnormalized)
    u16* whi   = (u16*)(attT + (size_t)BNC);         // 192*192 bf16
    u16* wlo   = whi + COUT_ * 2 * C_;               // 192*192 bf16
    float* y     = (float*)(wlo + COUT_ * 2 * C_);   // B*COUT*N fp32
    float* ss    = y + (size_t)B_ * COUT_ * N_;      // 2*COUT
    float* l_arr = ss + 2 * COUT_;                   // NTOK
    float* norm2 = l_arr + NTOK_;                    // NTOK
    int*   maxb  = (int*)(norm2 + NTOK_);            // 1
    float* pb    = attT;                             // 2*B*COUT partials (attT dead after conv)

    hipMemsetAsync(l_arr, 0, NTOK_ * sizeof(float), stream);
    hipMemsetAsync(norm2, 0, NTOK_ * sizeof(float), stream);
    hipMemsetAsync(attT, 0, (size_t)BNC * sizeof(float), stream);

    transpose_split<<<dim3(N_ / 32, C_ / 32, B_), 256, 0, stream>>>(x, xt_hi, xt_lo, xc_hi, norm2);
    cast_w<<<dim3((COUT_ * 2 * C_ + 255) / 256), 256, 0, stream>>>(w, whi, wlo);
    norm_max<<<dim3(1), 256, 0, stream>>>(norm2, maxb);
    flash_attn_mfma32<<<dim3((N_ + 127) / 128, B_, NSPLIT), 256, 0, stream>>>(
        xt_hi, xt_lo, xc_hi, norm2, maxb, attT, l_arr);
    conv_mfma<<<dim3(B_ * (N_ / 32)), 128, 0, stream>>>(x, attT, l_arr, whi, wlo, cb, y);
    bn_partial<<<dim3(COUT_, B_), 256, 0, stream>>>(y, pb);
    bn_finish<<<dim3(1), 192, 0, stream>>>(pb, gamma, beta, ss);
    bn_gelu_out<<<dim3((B_ * COUT_ * N_ / 4 + 255) / 256), 256, 0, stream>>>(y, ss, (float*)d_out);
}

// Round 7
// 237.323 us; speedup vs baseline: 2.2879x; 1.0045x over previous
//
#include <hip/hip_runtime.h>
#include <hip/hip_bf16.h>

// Problem constants
#define B_    8
#define C_    96
#define N_    3136      // 56*56
#define COUT_ 192
#define NTOK_ 25088     // B_*N_
#define BN_EPS 1e-5f

#define CROW 200        // conv cat LDS token-row stride in bf16 (192+8): 400B = 25*16 odd -> conflict-free
#define BNC  (B_ * N_ * C_)
#define NSPLIT 4
#define NT98  98        // 32-row K tiles per batch (3136/32)

// K2 LDS geometry (bytes), per buffer (V removed in R18 — direct-global):
//  Kh: 32 rows * 208B (13 chunks of 16B: 12 data + 1 pad; 13 odd -> bank-perm) = 6656, pad to 7*1024
//  Kl: same, at +7168
#define K2_KL_OFF 7168
#define K2_BUFSZ  14336

typedef __hip_bfloat16 bf16;
typedef unsigned short u16;
typedef unsigned int u32;
typedef __attribute__((ext_vector_type(8))) short short8;    // 8 bf16 = 16B (MFMA A/B frag)
typedef __attribute__((ext_vector_type(16))) float f32x16;   // 32x32 MFMA C/D frag

__device__ __forceinline__ u16 f2bf(float f) {
    union { __hip_bfloat16 h; u16 u; } cv;
    cv.h = __float2bfloat16(f);
    return cv.u;
}
__device__ __forceinline__ float bf2f(u16 v) {
    union { u16 u; __hip_bfloat16 h; } cv;
    cv.u = v;
    return __bfloat162float(cv.h);
}
__device__ __forceinline__ u32 packbf2(float lo, float hi) {
    return ((u32)f2bf(hi) << 16) | (u32)f2bf(lo);
}

// async global->LDS DMA, 16B per lane: LDS dest = WAVE-UNIFORM base + lane*16.
__device__ __forceinline__ void gload_lds16(const void* g, void* l) {
    __builtin_amdgcn_global_load_lds((const __attribute__((address_space(1))) void*)g,
                                     (__attribute__((address_space(3))) void*)l,
                                     16, 0, 0);
}

// ---------------------------------------------------------------------------
// K1: x [B][C][N] fp32 -> xt_hi/xt_lo [B][N][C] bf16 (token-major, hi/lo split)
//                         xc_hi [B][C][N] bf16 (channel-major, V read direct by K2)
// Fused: per-token squared-norm partial sums (32 channels per block) -> norm2.
__global__ __launch_bounds__(256) void transpose_split(const float* __restrict__ x,
                                                       u16* __restrict__ xt_hi,
                                                       u16* __restrict__ xt_lo,
                                                       u16* __restrict__ xc_hi,
                                                       float* __restrict__ norm2) {
    __shared__ float tile[32][33];
    __shared__ float nrm[32];
    const int nb = blockIdx.x * 32;
    const int cb = blockIdx.y * 32;
    const int b  = blockIdx.z;
    const int tid = threadIdx.x;
    const int tx = tid & 31;
    const int ty = tid >> 5;
    if (tid < 32) nrm[tid] = 0.0f;
    float psum = 0.0f;
#pragma unroll
    for (int r = 0; r < 32; r += 8) {
        size_t idx = ((size_t)b * C_ + cb + ty + r) * N_ + nb + tx;
        float v = x[idx];
        tile[ty + r][tx] = v;
        xc_hi[idx] = f2bf(v);
        psum = fmaf(v, v, psum);
    }
    __syncthreads();               // tile visible; nrm init done
    atomicAdd(&nrm[tx], psum);     // LDS atomic, 8 adders per slot
    // phase 2: token-major hi/lo writes, 2 channels per thread as one u32
#pragma unroll
    for (int it = 0; it < 2; it++) {
        const int n2 = (tid >> 4) + it * 16;   // token 0..31 within tile
        const int cp = tid & 15;               // channel pair 0..15
        float v0 = tile[2 * cp][n2];
        float v1 = tile[2 * cp + 1][n2];
        u16 h0 = f2bf(v0), h1 = f2bf(v1);
        u16 l0 = f2bf(v0 - bf2f(h0)), l1 = f2bf(v1 - bf2f(h1));
        size_t o = ((size_t)b * N_ + nb + n2) * C_ + cb + 2 * cp;
        *(u32*)&xt_hi[o] = (u32)h0 | ((u32)h1 << 16);
        *(u32*)&xt_lo[o] = (u32)l0 | ((u32)l1 << 16);
    }
    __syncthreads();               // nrm complete
    if (tid < 32)
        atomicAdd(&norm2[(size_t)b * N_ + nb + tid], nrm[tid]);
}

// K1b: conv_w [O][2C] fp32 -> whi/wlo bf16 (same [o][c] layout, hi/lo split)
__global__ __launch_bounds__(256) void cast_w(const float* __restrict__ w,
                                              u16* __restrict__ whi,
                                              u16* __restrict__ wlo) {
    int i = blockIdx.x * 256 + threadIdx.x;
    if (i >= COUT_ * 2 * C_) return;
    float v = w[i];
    u16 h = f2bf(v);
    whi[i] = h;
    wlo[i] = f2bf(v - bf2f(h));
}

// K1c: global max of norm2 — R18: multi-block (was single-block serial gate).
// norm2 >= 0 -> int-bits atomicMax == float max.
__global__ __launch_bounds__(256) void norm_max(const float* __restrict__ norm2,
                                                int* __restrict__ maxbits) {
    const int tid = blockIdx.x * 256 + threadIdx.x;
    float m = 0.0f;
    for (int i = tid; i < NTOK_; i += gridDim.x * 256) m = fmaxf(m, norm2[i]);
#pragma unroll
    for (int d = 1; d < 64; d <<= 1) m = fmaxf(m, __shfl_xor(m, d));
    if ((threadIdx.x & 63) == 0) atomicMax(maxbits, __float_as_int(m));
}

// ---------------------------------------------------------------------------
// K2: MFMA flash attention, transposed-S, 4-way split-K.
// R18: LDS-BW-bound per R16/R17 counters (reads 56 B/cy/CU + writes 17 vs
// ~85-110 ceiling; MfmaUtil 26% matches the 282KB/CU/tile-period model).
// Fix: V OUT of LDS -> 6 direct per-wave global loads/tile (L1-hot 6KB
// slice reused by 12 waves; issued at tile-top so ~2000cy QK covers them).
// LDS traffic/tile-period: reads 216->144KB, writes 66->42KB (-33/-36%).
// K staging (odd-stride 208B rows, conflict-free — verified R16: 16.9M->0)
// and the 1-barrier double-buffered pipeline unchanged.
__global__ __launch_bounds__(256, 3) void flash_attn_mfma32(const u16* __restrict__ xt_hi,
                                                            const u16* __restrict__ xt_lo,
                                                            const u16* __restrict__ xc_hi,
                                                            const float* __restrict__ norm2,
                                                            const int* __restrict__ maxbits,
                                                            float* __restrict__ attT,
                                                            float* __restrict__ l_arr) {
    __shared__ __align__(16) char LDSU[2][K2_BUFSZ];
    const int b     = blockIdx.y;
    const int i0    = blockIdx.x * 128;
    const int split = blockIdx.z;
    const int kt0   = (NT98 * split) / NSPLIT;
    const int kt1   = (NT98 * (split + 1)) / NSPLIT;
    const int tid   = threadIdx.x;
    const int lane  = tid & 63;
    const int w     = tid >> 6;
    const int col   = lane & 31;
    const int g     = lane >> 5;

    const u16* th = xt_hi + (size_t)b * N_ * C_;
    const u16* tl = xt_lo + (size_t)b * N_ * C_;
    const u16* vh = xc_hi + (size_t)b * C_ * N_;

    // Staging: 14 DMA slots of 1KB per buffer (Kh 0..6, Kl 7..13).
    // Wave w owns slots w+4j. Wave-uniform LDS dest (HW adds lane*16) +
    // per-lane global source offset (tile term added at issue).
    u32 loff[4], dofs[4];
#pragma unroll
    for (int j = 0; j < 4; j++) {
        int s = w + 4 * j;
        if (s >= 14) { loff[j] = 0; dofs[j] = 0; continue; }
        int kind = s < 7 ? 0 : 1;
        int t = s - kind * 7;
        int p = t * 64 + lane;    // physical 16B chunk 0..447
        int r = p / 13, c = p % 13;
        if (c > 11) c = 11;       // row pad chunk: duplicate read
        loff[j] = (r < 32) ? (u32)(r * 192 + c * 16) : 0u;   // tail pad
        dofs[j] = (u32)(kind * K2_KL_OFF + t * 1024);
    }

    // Q B-frags from global, once (lane holds its own q-row)
    const int qrow  = i0 + w * 32 + col;
    const int qrowc = qrow < N_ ? qrow : N_ - 1;
    short8 qh[6], ql[6];
#pragma unroll
    for (int kc = 0; kc < 6; kc++) {
        qh[kc] = *(const short8*)&th[(size_t)qrowc * C_ + kc * 16 + g * 8];
        ql[kc] = *(const short8*)&tl[(size_t)qrowc * C_ + kc * 16 + g * 8];
    }
    const float maxn2 = __int_as_float(*maxbits);
    const float m_i   = sqrtf(norm2[(size_t)b * N_ + qrowc] * maxn2);
    float l_acc = 0.0f;
    f32x16 O0 = {0}, O1 = {0}, O2 = {0};

    // stage K-tile kt into buffer nbuf (async DMA; drained at next barrier)
    auto stage = [&](int nbuf, int kt) {
        const u32 ktK = (u32)kt * 6144u;   // 32 rows * 192B
#pragma unroll
        for (int j = 0; j < 4; j++) {
            int s = w + 4 * j;
            if (s >= 14) break;
            const char* sb = (s < 7) ? (const char*)th + ktK
                                     : (const char*)tl + ktK;
            gload_lds16(sb + loff[j], (char*)&LDSU[nbuf][0] + dofs[j]);
        }
    };

    stage(0, kt0);
    __syncthreads();

    const int g16 = g * 16;
    int buf = 0;
    for (int kt = kt0; kt < kt1; kt++) {
        const int n0 = kt * 64 / 2;   // = kt*32 tokens
        // (1) prefetch next K-tile into back buffer (in flight across compute)
        if (kt + 1 < kt1) stage(buf ^ 1, kt + 1);

        // (2) V frags for THIS tile, direct from global (L1-hot slice);
        //     issued here so QK's ~2000cy covers the latency.
        short8 vf[6];
#pragma unroll
        for (int kc = 0; kc < 2; kc++)
#pragma unroll
            for (int j = 0; j < 3; j++)
                vf[kc * 3 + j] = *(const short8*)&vh[(size_t)(32 * j + col) * N_ +
                                                     kt * 32 + kc * 16 + g * 8];

        const char* Lb = (const char*)&LDSU[buf][0];

        // (3) QK^T: S[k=0..31][q=col], hi/lo split (3 MFMA per k-chunk)
        f32x16 S = {0};
        __builtin_amdgcn_s_setprio(1);
#pragma unroll
        for (int kc = 0; kc < 6; kc++) {
            const int o2 = col * 208 + kc * 32 + g16;
            short8 kh = *(const short8*)(Lb + o2);
            short8 kl = *(const short8*)(Lb + K2_KL_OFF + o2);
            S = __builtin_amdgcn_mfma_f32_32x32x16_bf16(kh, ql[kc], S, 0, 0, 0);
            S = __builtin_amdgcn_mfma_f32_32x32x16_bf16(kl, qh[kc], S, 0, 0, 0);
            S = __builtin_amdgcn_mfma_f32_32x32x16_bf16(kh, qh[kc], S, 0, 0, 0);
        }
        __builtin_amdgcn_s_setprio(0);

        // (4) softmax numerators + bf16 pack
        float p[16];
#pragma unroll
        for (int r = 0; r < 16; r++) {
            p[r] = __expf(S[r] - m_i);
            l_acc += p[r];
        }
        u32 w8[8];
#pragma unroll
        for (int q = 0; q < 8; q++) w8[q] = packbf2(p[2 * q], p[2 * q + 1]);

        // (5) PV from V regs
        __builtin_amdgcn_s_setprio(1);
#pragma unroll
        for (int kc = 0; kc < 2; kc++) {
            const int qb = kc * 4;
            u32 a0 = w8[qb + 0], a1 = w8[qb + 1];
            u32 a2 = w8[qb + 2], a3 = w8[qb + 3];
            u32 s0 = __shfl_xor((int)a0, 32), s1 = __shfl_xor((int)a1, 32);
            u32 s2 = __shfl_xor((int)a2, 32), s3 = __shfl_xor((int)a3, 32);
            union { short8 v; u32 u[4]; } Bf;
            Bf.u[0] = g ? s2 : a0;
            Bf.u[1] = g ? s3 : a1;
            Bf.u[2] = g ? a2 : s0;
            Bf.u[3] = g ? a3 : s1;
            O0 = __builtin_amdgcn_mfma_f32_32x32x16_bf16(vf[kc * 3 + 0], Bf.v, O0, 0, 0, 0);
            O1 = __builtin_amdgcn_mfma_f32_32x32x16_bf16(vf[kc * 3 + 1], Bf.v, O1, 0, 0, 0);
            O2 = __builtin_amdgcn_mfma_f32_32x32x16_bf16(vf[kc * 3 + 2], Bf.v, O2, 0, 0, 0);
        }
        __builtin_amdgcn_s_setprio(0);

        __syncthreads();     // drains my DMAs + all waves' LDS reads done
        buf ^= 1;
    }

    if (qrow < N_) {
        float* ab = attT + (size_t)b * C_ * N_ + qrow;
#pragma unroll
        for (int r = 0; r < 16; r++) {
            int c = (r & 3) + 8 * (r >> 2) + 4 * g;
            atomicAdd(&ab[(size_t)(c)      * N_], O0[r]);
            atomicAdd(&ab[(size_t)(c + 32) * N_], O1[r]);
            atomicAdd(&ab[(size_t)(c + 64) * N_], O2[r]);
        }
        float l_tot = l_acc + __shfl_xor(l_acc, 32);
        if (g == 0) atomicAdd(&l_arr[(size_t)b * N_ + qrow], l_tot);
    }
}

// ---------------------------------------------------------------------------
// K3: MFMA 1x1 conv (R17 32-token/128-thread version; unchanged this round)
__global__ __launch_bounds__(128, 3) void conv_mfma(const float* __restrict__ x,
                                                    const float* __restrict__ attT,
                                                    const float* __restrict__ l_arr,
                                                    const u16* __restrict__ whi,
                                                    const u16* __restrict__ wlo,
                                                    const float* __restrict__ convb,
                                                    float* __restrict__ y) {
    __shared__ u16 ch[32 * CROW];
    __shared__ u16 cl[32 * CROW];
    __shared__ float invl[32];
    const int b   = blockIdx.x / (N_ / 32);
    const int n0  = (blockIdx.x % (N_ / 32)) * 32;
    const int tid = threadIdx.x;

    if (tid < 32) invl[tid] = 1.0f / l_arr[(size_t)b * N_ + n0 + tid];
    __syncthreads();

    const float* xb = x    + (size_t)b * C_ * N_ + n0;
    const float* ab = attT + (size_t)b * C_ * N_ + n0;
    for (int e = tid; e < 32 * C_; e += 128) {
        int c = e >> 5, t = e & 31;
        float xv = xb[(size_t)c * N_ + t];
        float au = ab[(size_t)c * N_ + t];
        float xj = fmaxf(xv - au * invl[t], 0.0f);
        u16 h1 = f2bf(xv);
        ch[t * CROW + c] = h1;
        cl[t * CROW + c] = f2bf(xv - bf2f(h1));
        u16 h2 = f2bf(xj);
        ch[t * CROW + C_ + c] = h2;
        cl[t * CROW + C_ + c] = f2bf(xj - bf2f(h2));
    }
    __syncthreads();

    const int lane = tid & 63;
    const int w    = tid >> 6;        // 0..1
    const int col  = lane & 31;       // token within tile
    const int g    = lane >> 5;
    const int m0   = w * 3;           // wave's 3 m-tiles (96 channels)

    f32x16 A[3] = {{0}, {0}, {0}};
#pragma unroll
    for (int ks = 0; ks < 12; ks++) {
        const int k0 = ks * 16;
        short8 bh = *(const short8*)&ch[col * CROW + k0 + g * 8];
        short8 bl = *(const short8*)&cl[col * CROW + k0 + g * 8];
#pragma unroll
        for (int mt = 0; mt < 3; mt++) {
            const size_t wo = (size_t)((m0 + mt) * 32 + col) * (2 * C_) + k0 + g * 8;
            short8 ah = *(const short8*)&whi[wo];
            short8 al = *(const short8*)&wlo[wo];
            A[mt] = __builtin_amdgcn_mfma_f32_32x32x16_bf16(ah, bl, A[mt], 0, 0, 0);
            A[mt] = __builtin_amdgcn_mfma_f32_32x32x16_bf16(al, bh, A[mt], 0, 0, 0);
            A[mt] = __builtin_amdgcn_mfma_f32_32x32x16_bf16(ah, bh, A[mt], 0, 0, 0);
        }
    }

    float* yb = y + (size_t)b * COUT_ * N_ + n0 + col;
#pragma unroll
    for (int mt = 0; mt < 3; mt++)
#pragma unroll
        for (int r = 0; r < 16; r++) {
            int o = (m0 + mt) * 32 + (r & 3) + 8 * (r >> 2) + 4 * g;
            yb[(size_t)o * N_] = A[mt][r] + convb[o];
        }
}

// ---------------------------------------------------------------------------
// K4a: per-(b,channel) partial BN sums (distinct output lines, no contention)
__global__ __launch_bounds__(256) void bn_partial(const float* __restrict__ y,
                                                  float* __restrict__ pb) {
    const int o   = blockIdx.x;
    const int b   = blockIdx.y;
    const int tid = threadIdx.x;
    float s = 0.0f, q = 0.0f;
    const float4* p = (const float4*)(y + (size_t)(b * COUT_ + o) * N_);
    for (int i = tid; i < N_ / 4; i += 256) {
        float4 v = p[i];
        s += v.x + v.y + v.z + v.w;
        q += v.x * v.x + v.y * v.y + v.z * v.z + v.w * v.w;
    }
#pragma unroll
    for (int d = 1; d < 64; d <<= 1) {
        s += __shfl_xor(s, d);
        q += __shfl_xor(q, d);
    }
    __shared__ float wss[4], wqq[4];
    if ((tid & 63) == 0) { wss[tid >> 6] = s; wqq[tid >> 6] = q; }
    __syncthreads();
    if (tid == 0) {
        pb[b * COUT_ + o]                = wss[0] + wss[1] + wss[2] + wss[3];
        pb[B_ * COUT_ + b * COUT_ + o]   = wqq[0] + wqq[1] + wqq[2] + wqq[3];
    }
}

// K4b: reduce partials -> scale/shift
__global__ __launch_bounds__(192) void bn_finish(const float* __restrict__ pb,
                                                 const float* __restrict__ gamma,
                                                 const float* __restrict__ beta,
                                                 float* __restrict__ ss) {
    const int o = threadIdx.x;
    float s = 0.0f, q = 0.0f;
#pragma unroll
    for (int b = 0; b < B_; b++) {
        s += pb[b * COUT_ + o];
        q += pb[B_ * COUT_ + b * COUT_ + o];
    }
    const float invn = 1.0f / (float)NTOK_;
    float mean = s * invn;
    float var  = q * invn - mean * mean;
    float sc   = gamma[o] * rsqrtf(var + BN_EPS);
    ss[o]         = sc;
    ss[COUT_ + o] = beta[o] - mean * sc;
}

// K5: y -> BN affine -> exact GELU -> fp32 out
__global__ __launch_bounds__(256) void bn_gelu_out(const float* __restrict__ y,
                                                   const float* __restrict__ ss,
                                                   float* __restrict__ out) {
    const int total4 = (B_ * COUT_ * N_) / 4;
    int i = blockIdx.x * 256 + threadIdx.x;
    if (i >= total4) return;
    int base = i * 4;
    int o = (base / N_) % COUT_;
    float sc = ss[o], sh = ss[COUT_ + o];
    float4 v = *(const float4*)&y[base];
    float u0 = fmaf(v.x, sc, sh), u1 = fmaf(v.y, sc, sh);
    float u2 = fmaf(v.z, sc, sh), u3 = fmaf(v.w, sc, sh);
    const float k = 0.70710678118654752f;
    float4 g;
    g.x = 0.5f * u0 * (1.0f + erff(u0 * k));
    g.y = 0.5f * u1 * (1.0f + erff(u1 * k));
    g.z = 0.5f * u2 * (1.0f + erff(u2 * k));
    g.w = 0.5f * u3 * (1.0f + erff(u3 * k));
    *(float4*)&out[base] = g;
}

// ---------------------------------------------------------------------------
extern "C" void kernel_launch(void* const* d_in, const int* in_sizes, int n_in,
                              void* d_out, int out_size, void* d_ws, size_t ws_size,
                              hipStream_t stream) {
    const float* x     = (const float*)d_in[0];
    const float* w     = (const float*)d_in[1];
    const float* cb    = (const float*)d_in[2];
    const float* gamma = (const float*)d_in[3];
    const float* beta  = (const float*)d_in[4];

    u16* xt_hi = (u16*)d_ws;                         // BNC bf16
    u16* xt_lo = xt_hi + (size_t)BNC;                // BNC
    u16* xc_hi = xt_lo + (size_t)BNC;                // BNC
    float* attT  = (float*)(xc_hi + (size_t)BNC);    // BNC fp32 (channel-major, unnormalized)
    u16* whi   = (u16*)(attT + (size_t)BNC);         // 192*192 bf16
    u16* wlo   = whi + COUT_ * 2 * C_;               // 192*192 bf16
    float* y     = (float*)(wlo + COUT_ * 2 * C_);   // B*COUT*N fp32
    float* ss    = y + (size_t)B_ * COUT_ * N_;      // 2*COUT
    float* l_arr = ss + 2 * COUT_;                   // NTOK
    float* norm2 = l_arr + NTOK_;                    // NTOK
    int*   maxb  = (int*)(norm2 + NTOK_);            // 1
    float* pb    = attT;                             // 2*B*COUT partials (attT dead after conv)

    hipMemsetAsync(l_arr, 0, NTOK_ * sizeof(float), stream);
    hipMemsetAsync(norm2, 0, NTOK_ * sizeof(float), stream);
    hipMemsetAsync(maxb, 0, sizeof(int), stream);
    hipMemsetAsync(attT, 0, (size_t)BNC * sizeof(float), stream);

    transpose_split<<<dim3(N_ / 32, C_ / 32, B_), 256, 0, stream>>>(x, xt_hi, xt_lo, xc_hi, norm2);
    cast_w<<<dim3((COUT_ * 2 * C_ + 255) / 256), 256, 0, stream>>>(w, whi, wlo);
    norm_max<<<dim3(25), 256, 0, stream>>>(norm2, maxb);
    flash_attn_mfma32<<<dim3((N_ + 127) / 128, B_, NSPLIT), 256, 0, stream>>>(
        xt_hi, xt_lo, xc_hi, norm2, maxb, attT, l_arr);
    conv_mfma<<<dim3(B_ * (N_ / 32)), 128, 0, stream>>>(x, attT, l_arr, whi, wlo, cb, y);
    bn_partial<<<dim3(COUT_, B_), 256, 0, stream>>>(y, pb);
    bn_finish<<<dim3(1), 192, 0, stream>>>(pb, gamma, beta, ss);
    bn_gelu_out<<<dim3((B_ * COUT_ * N_ / 4 + 255) / 256), 256, 0, stream>>>(y, ss, (float*)d_out);
}

// Round 8
// 223.665 us; speedup vs baseline: 2.4276x; 1.0611x over previous
//
#include <hip/hip_runtime.h>
#include <hip/hip_bf16.h>

// Problem constants
#define B_    8
#define C_    96
#define N_    3136      // 56*56
#define COUT_ 192
#define NTOK_ 25088     // B_*N_
#define BN_EPS 1e-5f

#define CROW 200        // conv cat LDS token-row stride in bf16 (192+8): 400B = 25*16 odd -> conflict-free
#define BNC  (B_ * N_ * C_)
#define NSPLIT 4
#define NT98  98        // 32-row K tiles per batch (3136/32)

// K2 LDS geometry (bytes), per buffer (R16 layout — HW-verified conflict-free):
//  Kh: 32 rows * 208B (13 chunks of 16B: 12 data + 1 pad; 13 odd -> bank-perm) = 6656, pad to 7*1024
//  Kl: same, at +7168
//  V : 96 ch * 80B (5 chunks: 4 data + 1 pad) = 7680, pad to 8*1024, at +14336
#define K2_KL_OFF 7168
#define K2_V_OFF  14336
#define K2_BUFSZ  22528

typedef __hip_bfloat16 bf16;
typedef unsigned short u16;
typedef unsigned int u32;
typedef __attribute__((ext_vector_type(8))) short short8;    // 8 bf16 = 16B (MFMA A/B frag)
typedef __attribute__((ext_vector_type(16))) float f32x16;   // 32x32 MFMA C/D frag

__device__ __forceinline__ u16 f2bf(float f) {
    union { __hip_bfloat16 h; u16 u; } cv;
    cv.h = __float2bfloat16(f);
    return cv.u;
}
__device__ __forceinline__ float bf2f(u16 v) {
    union { u16 u; __hip_bfloat16 h; } cv;
    cv.u = v;
    return __bfloat162float(cv.h);
}
__device__ __forceinline__ u32 packbf2(float lo, float hi) {
    return ((u32)f2bf(hi) << 16) | (u32)f2bf(lo);
}

// async global->LDS DMA, 16B per lane: LDS dest = WAVE-UNIFORM base + lane*16.
__device__ __forceinline__ void gload_lds16(const void* g, void* l) {
    __builtin_amdgcn_global_load_lds((const __attribute__((address_space(1))) void*)g,
                                     (__attribute__((address_space(3))) void*)l,
                                     16, 0, 0);
}

// ---------------------------------------------------------------------------
// K1: x [B][C][N] fp32 -> xt_hi/xt_lo [B][N][C] bf16 (token-major, hi/lo split)
//                         xc_hi [B][C][N] bf16 (channel-major, V staged from here)
// Fused: per-token squared-norm partial sums (32 channels per block) -> norm2.
__global__ __launch_bounds__(256) void transpose_split(const float* __restrict__ x,
                                                       u16* __restrict__ xt_hi,
                                                       u16* __restrict__ xt_lo,
                                                       u16* __restrict__ xc_hi,
                                                       float* __restrict__ norm2) {
    __shared__ float tile[32][33];
    __shared__ float nrm[32];
    const int nb = blockIdx.x * 32;
    const int cb = blockIdx.y * 32;
    const int b  = blockIdx.z;
    const int tid = threadIdx.x;
    const int tx = tid & 31;
    const int ty = tid >> 5;
    if (tid < 32) nrm[tid] = 0.0f;
    float psum = 0.0f;
#pragma unroll
    for (int r = 0; r < 32; r += 8) {
        size_t idx = ((size_t)b * C_ + cb + ty + r) * N_ + nb + tx;
        float v = x[idx];
        tile[ty + r][tx] = v;
        xc_hi[idx] = f2bf(v);
        psum = fmaf(v, v, psum);
    }
    __syncthreads();               // tile visible; nrm init done
    atomicAdd(&nrm[tx], psum);     // LDS atomic, 8 adders per slot
    // phase 2: token-major hi/lo writes, 2 channels per thread as one u32
#pragma unroll
    for (int it = 0; it < 2; it++) {
        const int n2 = (tid >> 4) + it * 16;   // token 0..31 within tile
        const int cp = tid & 15;               // channel pair 0..15
        float v0 = tile[2 * cp][n2];
        float v1 = tile[2 * cp + 1][n2];
        u16 h0 = f2bf(v0), h1 = f2bf(v1);
        u16 l0 = f2bf(v0 - bf2f(h0)), l1 = f2bf(v1 - bf2f(h1));
        size_t o = ((size_t)b * N_ + nb + n2) * C_ + cb + 2 * cp;
        *(u32*)&xt_hi[o] = (u32)h0 | ((u32)h1 << 16);
        *(u32*)&xt_lo[o] = (u32)l0 | ((u32)l1 << 16);
    }
    __syncthreads();               // nrm complete
    if (tid < 32)
        atomicAdd(&norm2[(size_t)b * N_ + nb + tid], nrm[tid]);
}

// K1b: conv_w [O][2C] fp32 -> whi/wlo bf16 (same [o][c] layout, hi/lo split)
__global__ __launch_bounds__(256) void cast_w(const float* __restrict__ w,
                                              u16* __restrict__ whi,
                                              u16* __restrict__ wlo) {
    int i = blockIdx.x * 256 + threadIdx.x;
    if (i >= COUT_ * 2 * C_) return;
    float v = w[i];
    u16 h = f2bf(v);
    whi[i] = h;
    wlo[i] = f2bf(v - bf2f(h));
}

// K1c: global max of norm2 — multi-block (R18, kept: part of the −15us
// non-K2 gain). norm2 >= 0 -> int-bits atomicMax == float max.
__global__ __launch_bounds__(256) void norm_max(const float* __restrict__ norm2,
                                                int* __restrict__ maxbits) {
    const int tid = blockIdx.x * 256 + threadIdx.x;
    float m = 0.0f;
    for (int i = tid; i < NTOK_; i += gridDim.x * 256) m = fmaxf(m, norm2[i]);
#pragma unroll
    for (int d = 1; d < 64; d <<= 1) m = fmaxf(m, __shfl_xor(m, d));
    if ((threadIdx.x & 63) == 0) atomicMax(maxbits, __float_as_int(m));
}

// ---------------------------------------------------------------------------
// K2: MFMA flash attention, transposed-S, 4-way split-K.
// R19: EXACT R16 body restored (HW-verified 98.6us, conflicts 0). R18's
// V-direct-from-global regressed to 113us: per-wave V loads are scattered
// (32 cache lines/instr at stride 2N) and 4x redundant across waves —
// same failure as R13. V stays in LDS via contiguous DMA. Do NOT remove
// V from LDS; do NOT add scattered per-wave global loads to this kernel.
__global__ __launch_bounds__(256, 3) void flash_attn_mfma32(const u16* __restrict__ xt_hi,
                                                            const u16* __restrict__ xt_lo,
                                                            const u16* __restrict__ xc_hi,
                                                            const float* __restrict__ norm2,
                                                            const int* __restrict__ maxbits,
                                                            float* __restrict__ attT,
                                                            float* __restrict__ l_arr) {
    __shared__ __align__(16) char LDSU[2][K2_BUFSZ];
    const int b     = blockIdx.y;
    const int i0    = blockIdx.x * 128;
    const int split = blockIdx.z;
    const int kt0   = (NT98 * split) / NSPLIT;
    const int kt1   = (NT98 * (split + 1)) / NSPLIT;
    const int tid   = threadIdx.x;
    const int lane  = tid & 63;
    const int w     = tid >> 6;
    const int col   = lane & 31;
    const int g     = lane >> 5;

    const u16* th = xt_hi + (size_t)b * N_ * C_;
    const u16* tl = xt_lo + (size_t)b * N_ * C_;
    const u16* vh = xc_hi + (size_t)b * C_ * N_;

    // Staging: 22 DMA slots of 1KB per buffer (Kh 0..6, Kl 7..13, V 14..21).
    // Wave w owns slots w+4j. Wave-uniform LDS dest (HW adds lane*16) +
    // per-lane global source offset (tile term added at issue).
    u32 loff[6], dofs[6];
#pragma unroll
    for (int j = 0; j < 6; j++) {
        int s = w + 4 * j;
        if (s >= 22) { loff[j] = 0; dofs[j] = 0; continue; }
        if (s < 14) {                 // K hi/lo
            int kind = s < 7 ? 0 : 1;
            int t = s - kind * 7;
            int p = t * 64 + lane;    // physical 16B chunk 0..447
            int r = p / 13, c = p % 13;
            if (c > 11) c = 11;       // row pad chunk: duplicate read
            loff[j] = (r < 32) ? (u32)(r * 192 + c * 16) : 0u;   // tail pad
            dofs[j] = (u32)(kind * K2_KL_OFF + t * 1024);
        } else {                      // V
            int t = s - 14;
            int p = t * 64 + lane;    // 0..511
            int ch = p / 5, c = p % 5;
            if (c > 3) c = 3;
            loff[j] = (ch < 96) ? (u32)(ch * (N_ * 2) + c * 16) : 0u;
            dofs[j] = (u32)(K2_V_OFF + t * 1024);
        }
    }

    // Q B-frags from global, once (lane holds its own q-row)
    const int qrow  = i0 + w * 32 + col;
    const int qrowc = qrow < N_ ? qrow : N_ - 1;
    short8 qh[6], ql[6];
#pragma unroll
    for (int kc = 0; kc < 6; kc++) {
        qh[kc] = *(const short8*)&th[(size_t)qrowc * C_ + kc * 16 + g * 8];
        ql[kc] = *(const short8*)&tl[(size_t)qrowc * C_ + kc * 16 + g * 8];
    }
    const float maxn2 = __int_as_float(*maxbits);
    const float m_i   = sqrtf(norm2[(size_t)b * N_ + qrowc] * maxn2);
    float l_acc = 0.0f;
    f32x16 O0 = {0}, O1 = {0}, O2 = {0};

    // stage tile kt into buffer nbuf (async DMA; drained at next barrier)
    auto stage = [&](int nbuf, int kt) {
        const u32 ktK = (u32)kt * 6144u;   // 32 rows * 192B
        const u32 ktV = (u32)kt * 64u;     // 32 tokens * 2B
#pragma unroll
        for (int j = 0; j < 6; j++) {
            int s = w + 4 * j;
            if (s >= 22) break;
            const char* sb = (s < 7)  ? (const char*)th + ktK
                           : (s < 14) ? (const char*)tl + ktK
                                      : (const char*)vh + ktV;
            gload_lds16(sb + loff[j], (char*)&LDSU[nbuf][0] + dofs[j]);
        }
    };

    stage(0, kt0);
    __syncthreads();

    const int g16 = g * 16;
    int buf = 0;
    for (int kt = kt0; kt < kt1; kt++) {
        // (1) prefetch next tile into back buffer (in flight across compute)
        if (kt + 1 < kt1) stage(buf ^ 1, kt + 1);

        const char* Lb = (const char*)&LDSU[buf][0];

        // (2) QK^T: S[k=0..31][q=col], hi/lo split (3 MFMA per k-chunk)
        f32x16 S = {0};
        __builtin_amdgcn_s_setprio(1);
#pragma unroll
        for (int kc = 0; kc < 6; kc++) {
            const int o2 = col * 208 + kc * 32 + g16;
            short8 kh = *(const short8*)(Lb + o2);
            short8 kl = *(const short8*)(Lb + K2_KL_OFF + o2);
            S = __builtin_amdgcn_mfma_f32_32x32x16_bf16(kh, ql[kc], S, 0, 0, 0);
            S = __builtin_amdgcn_mfma_f32_32x32x16_bf16(kl, qh[kc], S, 0, 0, 0);
            S = __builtin_amdgcn_mfma_f32_32x32x16_bf16(kh, qh[kc], S, 0, 0, 0);
        }
        __builtin_amdgcn_s_setprio(0);

        // (3) softmax numerators + bf16 pack
        float p[16];
#pragma unroll
        for (int r = 0; r < 16; r++) {
            p[r] = __expf(S[r] - m_i);
            l_acc += p[r];
        }
        u32 w8[8];
#pragma unroll
        for (int q = 0; q < 8; q++) w8[q] = packbf2(p[2 * q], p[2 * q + 1]);

        // (4) PV from V-LDS (rows 80B: conflict-free)
        __builtin_amdgcn_s_setprio(1);
#pragma unroll
        for (int kc = 0; kc < 2; kc++) {
            const int qb = kc * 4;
            u32 a0 = w8[qb + 0], a1 = w8[qb + 1];
            u32 a2 = w8[qb + 2], a3 = w8[qb + 3];
            u32 s0 = __shfl_xor((int)a0, 32), s1 = __shfl_xor((int)a1, 32);
            u32 s2 = __shfl_xor((int)a2, 32), s3 = __shfl_xor((int)a3, 32);
            union { short8 v; u32 u[4]; } Bf;
            Bf.u[0] = g ? s2 : a0;
            Bf.u[1] = g ? s3 : a1;
            Bf.u[2] = g ? a2 : s0;
            Bf.u[3] = g ? a3 : s1;
            const int vo = K2_V_OFF + col * 80 + kc * 32 + g16;
            short8 v0 = *(const short8*)(Lb + vo);
            short8 v1 = *(const short8*)(Lb + vo + 2560);   // +32 ch * 80B
            short8 v2 = *(const short8*)(Lb + vo + 5120);   // +64 ch * 80B
            O0 = __builtin_amdgcn_mfma_f32_32x32x16_bf16(v0, Bf.v, O0, 0, 0, 0);
            O1 = __builtin_amdgcn_mfma_f32_32x32x16_bf16(v1, Bf.v, O1, 0, 0, 0);
            O2 = __builtin_amdgcn_mfma_f32_32x32x16_bf16(v2, Bf.v, O2, 0, 0, 0);
        }
        __builtin_amdgcn_s_setprio(0);

        __syncthreads();     // drains my DMAs + all waves' LDS reads done
        buf ^= 1;
    }

    if (qrow < N_) {
        float* ab = attT + (size_t)b * C_ * N_ + qrow;
#pragma unroll
        for (int r = 0; r < 16; r++) {
            int c = (r & 3) + 8 * (r >> 2) + 4 * g;
            atomicAdd(&ab[(size_t)(c)      * N_], O0[r]);
            atomicAdd(&ab[(size_t)(c + 32) * N_], O1[r]);
            atomicAdd(&ab[(size_t)(c + 64) * N_], O2[r]);
        }
        float l_tot = l_acc + __shfl_xor(l_acc, 32);
        if (g == 0) atomicAdd(&l_arr[(size_t)b * N_ + qrow], l_tot);
    }
}

// ---------------------------------------------------------------------------
// K3: MFMA 1x1 conv (R17 32-token/128-thread version; unchanged this round)
__global__ __launch_bounds__(128, 3) void conv_mfma(const float* __restrict__ x,
                                                    const float* __restrict__ attT,
                                                    const float* __restrict__ l_arr,
                                                    const u16* __restrict__ whi,
                                                    const u16* __restrict__ wlo,
                                                    const float* __restrict__ convb,
                                                    float* __restrict__ y) {
    __shared__ u16 ch[32 * CROW];
    __shared__ u16 cl[32 * CROW];
    __shared__ float invl[32];
    const int b   = blockIdx.x / (N_ / 32);
    const int n0  = (blockIdx.x % (N_ / 32)) * 32;
    const int tid = threadIdx.x;

    if (tid < 32) invl[tid] = 1.0f / l_arr[(size_t)b * N_ + n0 + tid];
    __syncthreads();

    const float* xb = x    + (size_t)b * C_ * N_ + n0;
    const float* ab = attT + (size_t)b * C_ * N_ + n0;
    for (int e = tid; e < 32 * C_; e += 128) {
        int c = e >> 5, t = e & 31;
        float xv = xb[(size_t)c * N_ + t];
        float au = ab[(size_t)c * N_ + t];
        float xj = fmaxf(xv - au * invl[t], 0.0f);
        u16 h1 = f2bf(xv);
        ch[t * CROW + c] = h1;
        cl[t * CROW + c] = f2bf(xv - bf2f(h1));
        u16 h2 = f2bf(xj);
        ch[t * CROW + C_ + c] = h2;
        cl[t * CROW + C_ + c] = f2bf(xj - bf2f(h2));
    }
    __syncthreads();

    const int lane = tid & 63;
    const int w    = tid >> 6;        // 0..1
    const int col  = lane & 31;       // token within tile
    const int g    = lane >> 5;
    const int m0   = w * 3;           // wave's 3 m-tiles (96 channels)

    f32x16 A[3] = {{0}, {0}, {0}};
#pragma unroll
    for (int ks = 0; ks < 12; ks++) {
        const int k0 = ks * 16;
        short8 bh = *(const short8*)&ch[col * CROW + k0 + g * 8];
        short8 bl = *(const short8*)&cl[col * CROW + k0 + g * 8];
#pragma unroll
        for (int mt = 0; mt < 3; mt++) {
            const size_t wo = (size_t)((m0 + mt) * 32 + col) * (2 * C_) + k0 + g * 8;
            short8 ah = *(const short8*)&whi[wo];
            short8 al = *(const short8*)&wlo[wo];
            A[mt] = __builtin_amdgcn_mfma_f32_32x32x16_bf16(ah, bl, A[mt], 0, 0, 0);
            A[mt] = __builtin_amdgcn_mfma_f32_32x32x16_bf16(al, bh, A[mt], 0, 0, 0);
            A[mt] = __builtin_amdgcn_mfma_f32_32x32x16_bf16(ah, bh, A[mt], 0, 0, 0);
        }
    }

    float* yb = y + (size_t)b * COUT_ * N_ + n0 + col;
#pragma unroll
    for (int mt = 0; mt < 3; mt++)
#pragma unroll
        for (int r = 0; r < 16; r++) {
            int o = (m0 + mt) * 32 + (r & 3) + 8 * (r >> 2) + 4 * g;
            yb[(size_t)o * N_] = A[mt][r] + convb[o];
        }
}

// ---------------------------------------------------------------------------
// K4a: per-(b,channel) partial BN sums (distinct output lines, no contention)
__global__ __launch_bounds__(256) void bn_partial(const float* __restrict__ y,
                                                  float* __restrict__ pb) {
    const int o   = blockIdx.x;
    const int b   = blockIdx.y;
    const int tid = threadIdx.x;
    float s = 0.0f, q = 0.0f;
    const float4* p = (const float4*)(y + (size_t)(b * COUT_ + o) * N_);
    for (int i = tid; i < N_ / 4; i += 256) {
        float4 v = p[i];
        s += v.x + v.y + v.z + v.w;
        q += v.x * v.x + v.y * v.y + v.z * v.z + v.w * v.w;
    }
#pragma unroll
    for (int d = 1; d < 64; d <<= 1) {
        s += __shfl_xor(s, d);
        q += __shfl_xor(q, d);
    }
    __shared__ float wss[4], wqq[4];
    if ((tid & 63) == 0) { wss[tid >> 6] = s; wqq[tid >> 6] = q; }
    __syncthreads();
    if (tid == 0) {
        pb[b * COUT_ + o]                = wss[0] + wss[1] + wss[2] + wss[3];
        pb[B_ * COUT_ + b * COUT_ + o]   = wqq[0] + wqq[1] + wqq[2] + wqq[3];
    }
}

// K4b: reduce partials -> scale/shift
__global__ __launch_bounds__(192) void bn_finish(const float* __restrict__ pb,
                                                 const float* __restrict__ gamma,
                                                 const float* __restrict__ beta,
                                                 float* __restrict__ ss) {
    const int o = threadIdx.x;
    float s = 0.0f, q = 0.0f;
#pragma unroll
    for (int b = 0; b < B_; b++) {
        s += pb[b * COUT_ + o];
        q += pb[B_ * COUT_ + b * COUT_ + o];
    }
    const float invn = 1.0f / (float)NTOK_;
    float mean = s * invn;
    float var  = q * invn - mean * mean;
    float sc   = gamma[o] * rsqrtf(var + BN_EPS);
    ss[o]         = sc;
    ss[COUT_ + o] = beta[o] - mean * sc;
}

// K5: y -> BN affine -> exact GELU -> fp32 out
__global__ __launch_bounds__(256) void bn_gelu_out(const float* __restrict__ y,
                                                   const float* __restrict__ ss,
                                                   float* __restrict__ out) {
    const int total4 = (B_ * COUT_ * N_) / 4;
    int i = blockIdx.x * 256 + threadIdx.x;
    if (i >= total4) return;
    int base = i * 4;
    int o = (base / N_) % COUT_;
    float sc = ss[o], sh = ss[COUT_ + o];
    float4 v = *(const float4*)&y[base];
    float u0 = fmaf(v.x, sc, sh), u1 = fmaf(v.y, sc, sh);
    float u2 = fmaf(v.z, sc, sh), u3 = fmaf(v.w, sc, sh);
    const float k = 0.70710678118654752f;
    float4 g;
    g.x = 0.5f * u0 * (1.0f + erff(u0 * k));
    g.y = 0.5f * u1 * (1.0f + erff(u1 * k));
    g.z = 0.5f * u2 * (1.0f + erff(u2 * k));
    g.w = 0.5f * u3 * (1.0f + erff(u3 * k));
    *(float4*)&out[base] = g;
}

// ---------------------------------------------------------------------------
extern "C" void kernel_launch(void* const* d_in, const int* in_sizes, int n_in,
                              void* d_out, int out_size, void* d_ws, size_t ws_size,
                              hipStream_t stream) {
    const float* x     = (const float*)d_in[0];
    const float* w     = (const float*)d_in[1];
    const float* cb    = (const float*)d_in[2];
    const float* gamma = (const float*)d_in[3];
    const float* beta  = (const float*)d_in[4];

    u16* xt_hi = (u16*)d_ws;                         // BNC bf16
    u16* xt_lo = xt_hi + (size_t)BNC;                // BNC
    u16* xc_hi = xt_lo + (size_t)BNC;                // BNC
    float* attT  = (float*)(xc_hi + (size_t)BNC);    // BNC fp32 (channel-major, unnormalized)
    u16* whi   = (u16*)(attT + (size_t)BNC);         // 192*192 bf16
    u16* wlo   = whi + COUT_ * 2 * C_;               // 192*192 bf16
    float* y     = (float*)(wlo + COUT_ * 2 * C_);   // B*COUT*N fp32
    float* ss    = y + (size_t)B_ * COUT_ * N_;      // 2*COUT
    float* l_arr = ss + 2 * COUT_;                   // NTOK
    float* norm2 = l_arr + NTOK_;                    // NTOK
    int*   maxb  = (int*)(norm2 + NTOK_);            // 1
    float* pb    = attT;                             // 2*B*COUT partials (attT dead after conv)

    hipMemsetAsync(l_arr, 0, NTOK_ * sizeof(float), stream);
    hipMemsetAsync(norm2, 0, NTOK_ * sizeof(float), stream);
    hipMemsetAsync(maxb, 0, sizeof(int), stream);
    hipMemsetAsync(attT, 0, (size_t)BNC * sizeof(float), stream);

    transpose_split<<<dim3(N_ / 32, C_ / 32, B_), 256, 0, stream>>>(x, xt_hi, xt_lo, xc_hi, norm2);
    cast_w<<<dim3((COUT_ * 2 * C_ + 255) / 256), 256, 0, stream>>>(w, whi, wlo);
    norm_max<<<dim3(25), 256, 0, stream>>>(norm2, maxb);
    flash_attn_mfma32<<<dim3((N_ + 127) / 128, B_, NSPLIT), 256, 0, stream>>>(
        xt_hi, xt_lo, xc_hi, norm2, maxb, attT, l_arr);
    conv_mfma<<<dim3(B_ * (N_ / 32)), 128, 0, stream>>>(x, attT, l_arr, whi, wlo, cb, y);
    bn_partial<<<dim3(COUT_, B_), 256, 0, stream>>>(y, pb);
    bn_finish<<<dim3(1), 192, 0, stream>>>(pb, gamma, beta, ss);
    bn_gelu_out<<<dim3((B_ * COUT_ * N_ / 4 + 255) / 256), 256, 0, stream>>>(y, ss, (float*)d_out);
}